// Round 14
// baseline (1062.427 us; speedup 1.0000x reference)
//
#include <hip/hip_runtime.h>
#include <hip/hip_bf16.h>

typedef __hip_bfloat16 bf16;
typedef __attribute__((ext_vector_type(8))) short bf8v;   // 8 bf16 (4 VGPR)
typedef __attribute__((ext_vector_type(4))) float f32x4;  // MFMA acc

// flag: 1 = float tensors are bf16, 0 = fp32
__device__ __forceinline__ float ldw(const void* p, long i, int isbf) {
    return isbf ? __bfloat162float(((const bf16*)p)[i]) : ((const float*)p)[i];
}
__device__ __forceinline__ unsigned short f2bf(float v) {
    bf16 h = __float2bfloat16(v);
    return *reinterpret_cast<unsigned short*>(&h);
}
__device__ __forceinline__ float bfu2f(unsigned short u) {
    return __uint_as_float((unsigned)u << 16);
}

// ---------------------------------------------------------------- dtype detect
__global__ void k_detect(const unsigned short* __restrict__ w, int n, int* __restrict__ flag) {
    __shared__ int cnt;
    if (threadIdx.x == 0) cnt = 0;
    __syncthreads();
    int bad = 0;
    for (int i = threadIdx.x; i < n; i += 256) {
        int e = (w[i] >> 7) & 0xFF;
        if (e == 0xFF || (e != 0 && (e < 64 || e > 190))) bad++;
    }
    atomicAdd(&cnt, bad);
    __syncthreads();
    if (threadIdx.x == 0) *flag = (cnt > n / 16) ? 0 : 1;
}

// ---------------------------------------------------------------- small utils
__global__ void k_cvt_in(const void* __restrict__ s, float* __restrict__ d, int n,
                         const int* __restrict__ flag) {
    int i = blockIdx.x * 256 + threadIdx.x;
    if (i < n) d[i] = ldw(s, i, *flag);
}
__global__ void k_out(const float* __restrict__ s, void* __restrict__ d, int n,
                      const int* __restrict__ flag) {
    int i = blockIdx.x * 256 + threadIdx.x;
    if (i < n) {
        if (*flag) ((bf16*)d)[i] = __float2bfloat16(s[i]);
        else       ((float*)d)[i] = s[i];
    }
}
__global__ void k_zero(float* __restrict__ d, int n) {
    int i = blockIdx.x * 256 + threadIdx.x;
    if (i < n) d[i] = 0.f;
}
__global__ void k_zero_i(int* __restrict__ d, int n) {
    int i = blockIdx.x * 256 + threadIdx.x;
    if (i < n) d[i] = 0;
}
// pack (x,y,z) triplets -> float4 (x,y,z,|p|^2)
__global__ void k_pack4(const float* __restrict__ p, float4* __restrict__ o, int n) {
    int i = blockIdx.x * 256 + threadIdx.x;
    if (i < n) {
        float x = p[3 * i], y = p[3 * i + 1], z = p[3 * i + 2];
        float4 v = {x, y, z, fmaf(x, x, fmaf(y, y, z * z))};
        o[i] = v;
    }
}

// ---------------------------------------------------------------- CSR build
__global__ void k_count(const int* __restrict__ dst, int* __restrict__ cnt, int E) {
    int i = blockIdx.x * 256 + threadIdx.x;
    if (i < E) atomicAdd(&cnt[dst[i]], 1);
}
__global__ void k_dinv_i(const int* __restrict__ cnt, float* __restrict__ dinv, int n) {
    int i = blockIdx.x * 256 + threadIdx.x;
    if (i < n) dinv[i] = rsqrtf((float)cnt[i] + 1.0f);  // +1 self loop
}
// single block, 1024 threads, exclusive scan of cnt[0..n) -> offs, offs[n]=E
__global__ __launch_bounds__(1024) void k_scan(const int* __restrict__ cnt,
                                               int* __restrict__ offs, int n) {
    __shared__ int sm[1024];
    int t = threadIdx.x;
    int chunk = (n + 1023) >> 10;
    int b0 = t * chunk, b1 = min(b0 + chunk, n);
    int s = 0;
    for (int i = b0; i < b1; i++) s += cnt[i];
    sm[t] = s;
    __syncthreads();
    for (int o = 1; o < 1024; o <<= 1) {
        int v = (t >= o) ? sm[t - o] : 0;
        __syncthreads();
        sm[t] += v;
        __syncthreads();
    }
    int run = sm[t] - s;  // exclusive
    for (int i = b0; i < b1; i++) { offs[i] = run; run += cnt[i]; }
    if (t == 1023) offs[n] = sm[1023];
}
__global__ void k_fill(const int* __restrict__ src, const int* __restrict__ dst,
                       const int* __restrict__ offs, int* __restrict__ cur,
                       int* __restrict__ bkt, int E) {
    int e = blockIdx.x * 256 + threadIdx.x;
    if (e < E) {
        int d = dst[e];
        int p = atomicAdd(&cur[d], 1);
        bkt[offs[d] + p] = src[e];
    }
}

// ---------------------------------------------------------------- weight transpose + hi/lo split
// W (KxN, flagged dtype, offset woff) -> WTh/WTl (N x Kpad bf16), zero-pad k>=K
// grid (N/32, Kpad/32), 256 threads
__global__ __launch_bounds__(256) void k_wt(const void* __restrict__ W, long woff,
                                            unsigned short* __restrict__ WTh,
                                            unsigned short* __restrict__ WTl,
                                            int K, int N, int Kpad,
                                            const int* __restrict__ flag) {
    __shared__ unsigned short th[32][33];
    __shared__ unsigned short tl[32][33];
    const int isbf = *flag;
    int n0 = blockIdx.x * 32, k0 = blockIdx.y * 32;
    int c = threadIdx.x & 31, r = threadIdx.x >> 5;   // r 0..7
    #pragma unroll
    for (int u = 0; u < 4; u++) {
        int k = k0 + r + u * 8;
        float v = (k < K) ? ldw(W, woff + (long)k * N + n0 + c, isbf) : 0.f;
        unsigned short h = f2bf(v);
        th[r + u * 8][c] = h;
        tl[r + u * 8][c] = f2bf(v - bfu2f(h));
    }
    __syncthreads();
    #pragma unroll
    for (int u = 0; u < 4; u++) {
        int n = n0 + r + u * 8;
        WTh[(long)n * Kpad + k0 + c] = th[c][r + u * 8];
        WTl[(long)n * Kpad + k0 + c] = tl[c][r + u * 8];
    }
}

// ---------------------------------------------------------------- matmul (fp32, generic)
__global__ __launch_bounds__(256) void k_mm(
    const float* __restrict__ A, const void* __restrict__ Wt,
    const void* __restrict__ bias, const float* __restrict__ radd,
    const float* __restrict__ rsc, const float* __restrict__ rs,
    float* __restrict__ C, int M, int K, int N, long woff, int relu,
    const int* __restrict__ flag)
{
    __shared__ float As[2][16][68];
    __shared__ float Bs[2][16][68];
    const int isbf = *flag;
    const int tid = threadIdx.x;
    const int tx = tid & 15, ty = tid >> 4;
    const int bx = blockIdx.x, by = blockIdx.y;

    const int ar = tid >> 2, aq = (tid & 3) << 2;
    const long arow = (long)(by * 64 + ar) * K;
    const int bkk = tid >> 4, bn4 = (tid & 15) << 2;
    const int bcol0 = bx * 64 + bn4;

    float acc[4][4] = {};
    float4 pa, pb;

    auto loadAB = [&](int k0) {
        int kg = k0 + aq;
        pa.x = (kg + 0 < K) ? A[arow + kg + 0] : 0.f;
        pa.y = (kg + 1 < K) ? A[arow + kg + 1] : 0.f;
        pa.z = (kg + 2 < K) ? A[arow + kg + 2] : 0.f;
        pa.w = (kg + 3 < K) ? A[arow + kg + 3] : 0.f;
        int kb = k0 + bkk;
        pb = make_float4(0.f, 0.f, 0.f, 0.f);
        if (kb < K) {
            long base = woff + (long)kb * N + bcol0;
            if (bcol0 + 3 < N) {
                pb.x = ldw(Wt, base + 0, isbf); pb.y = ldw(Wt, base + 1, isbf);
                pb.z = ldw(Wt, base + 2, isbf); pb.w = ldw(Wt, base + 3, isbf);
            } else {
                if (bcol0 < N)     pb.x = ldw(Wt, base + 0, isbf);
                if (bcol0 + 1 < N) pb.y = ldw(Wt, base + 1, isbf);
                if (bcol0 + 2 < N) pb.z = ldw(Wt, base + 2, isbf);
            }
        }
    };
    auto storeAB = [&](int b) {
        As[b][aq + 0][ar] = pa.x;  As[b][aq + 1][ar] = pa.y;
        As[b][aq + 2][ar] = pa.z;  As[b][aq + 3][ar] = pa.w;
        *(float4*)&Bs[b][bkk][bn4] = pb;
    };

    loadAB(0);
    storeAB(0);
    __syncthreads();

    const int nk = (K + 15) >> 4;
    for (int t = 0; t < nk; t++) {
        const int cur = t & 1;
        const bool more = (t + 1 < nk);
        if (more) loadAB((t + 1) << 4);
        #pragma unroll
        for (int kk = 0; kk < 16; kk++) {
            float4 a = *(const float4*)&As[cur][kk][ty << 2];
            float4 b = *(const float4*)&Bs[cur][kk][tx << 2];
            float av[4] = {a.x, a.y, a.z, a.w};
            float bv[4] = {b.x, b.y, b.z, b.w};
            #pragma unroll
            for (int i = 0; i < 4; i++)
                #pragma unroll
                for (int j = 0; j < 4; j++)
                    acc[i][j] = fmaf(av[i], bv[j], acc[i][j]);
        }
        if (more) storeAB(cur ^ 1);
        __syncthreads();
    }

    const int col = bx * 64 + (tx << 2);
    #pragma unroll
    for (int i = 0; i < 4; i++) {
        int r = by * 64 + (ty << 2) + i;
        float m = rs ? rs[r] : 1.0f;
        float rr = rsc ? rsc[r] : 1.0f;
        float v[4];
        #pragma unroll
        for (int j = 0; j < 4; j++) {
            v[j] = acc[i][j] * m;
            int c = col + j;
            if (c < N) {
                if (bias) v[j] += ldw(bias, c, isbf);
                if (radd) v[j] += radd[c] * rr;
            }
            if (relu) v[j] = fmaxf(v[j], 0.f);
        }
        if (col + 3 < N) {
            float4 o = {v[0], v[1], v[2], v[3]};
            *(float4*)&C[(long)r * N + col] = o;
        } else {
            for (int j = 0; j < 4; j++)
                if (col + j < N) C[(long)r * N + col + j] = v[j];
        }
    }
}

// ---------------------------------------------------------------- matmul (MFMA bf16x3)
// fp32 accuracy via hi/lo bf16 split: a*b ~= al*bh + ah*bl + ah*bh (fp32 accum).
// Round 14: 2-deep register prefetch at 512 threads. Round 13's occupancy
// doubling was null (MfmaUtil flat 19%): all blocks run the K-loop in
// lockstep, so every block stalls on st()'s vmcnt wait simultaneously —
// TLP can't hide a globally-synchronized stall. Fix = prefetch DEPTH:
// loads for tile t+2 issued at tile t (cover = 2 compute phases ~900cyc
// = HBM latency). Affordable now: 8 k/thread staging = 16 VGPR/set, two
// named sets = 32 VGPR (r9's failed 2-deep needed 64 at 256 thr).
// launch_bounds(512,6): VGPR cap ~84 (est. use ~65) -> no spill;
// 3 blocks/CU. Accumulation order unchanged.
__global__ __launch_bounds__(512, 6) void k_mmx(
    const float* __restrict__ A,
    const unsigned short* __restrict__ WTh, const unsigned short* __restrict__ WTl,
    const void* __restrict__ bias, const float* __restrict__ radd,
    const float* __restrict__ rsc, const float* __restrict__ rs,
    float* __restrict__ C, int M, int K, int Kpad, int N, int relu,
    const int* __restrict__ flag)
{
    __shared__ unsigned short Ash[64][72];
    __shared__ unsigned short Asl[64][72];
    __shared__ unsigned short Bsh[64][72];
    __shared__ unsigned short Bsl[64][72];
    const int tid = threadIdx.x;
    // XCD-aware swizzle (FETCH 75->19MB measured); bijective iff nwg%8==0.
    const int nbx = gridDim.x;
    int id = blockIdx.y * nbx + blockIdx.x;
    {
        int nwg = nbx * gridDim.y;
        if ((nwg & 7) == 0) {
            int xcd = id & 7, pos = id >> 3;
            id = xcd * (nwg >> 3) + pos;
        }
    }
    const int bx = id % nbx, by = id / nbx;
    const int lane = tid & 63, wid = tid >> 6;       // wid 0..7
    const int wr = wid >> 2, wc = wid & 3;           // 2 x 4 wave layout
    const int lr = lane & 15, lg = lane >> 4;
    const int ar = tid >> 3, aq = (tid & 7) << 3;    // 8 consecutive k per thread
    const long arow = (long)(by * 64 + ar) * K;
    const unsigned short* wrh = WTh + (long)(bx * 64 + ar) * Kpad;
    const unsigned short* wrl = WTl + (long)(bx * 64 + ar) * Kpad;
    const bool k4 = (K & 3) == 0;
    const bool k2 = (K & 1) == 0;

    f32x4 acc0 = {0,0,0,0}, acc1 = {0,0,0,0};
    // two named prefetch sets (static selection only; 16 VGPR each)
    float4 paA0, paA1, paB0, paB1;
    bf8v pbhA, pblA, pbhB, pblB;

    auto ldA = [&](int k0) {             // issue loads ONLY — no use of results
        int kg = k0 + aq;
        if (k4 && kg + 7 < K) {
            paA0 = *(const float4*)&A[arow + kg];
            paA1 = *(const float4*)&A[arow + kg + 4];
        } else if (k2 && kg + 7 < K) {
            float2 f0 = *(const float2*)&A[arow + kg];
            float2 f1 = *(const float2*)&A[arow + kg + 2];
            float2 f2 = *(const float2*)&A[arow + kg + 4];
            float2 f3 = *(const float2*)&A[arow + kg + 6];
            paA0 = make_float4(f0.x, f0.y, f1.x, f1.y);
            paA1 = make_float4(f2.x, f2.y, f3.x, f3.y);
        } else {
            float t[8];
            #pragma unroll
            for (int e = 0; e < 8; e++) t[e] = (kg + e < K) ? A[arow + kg + e] : 0.f;
            paA0 = *(float4*)&t[0];  paA1 = *(float4*)&t[4];
        }
        pbhA = *(const bf8v*)(wrh + kg);
        pblA = *(const bf8v*)(wrl + kg);
    };
    auto ldB = [&](int k0) {
        int kg = k0 + aq;
        if (k4 && kg + 7 < K) {
            paB0 = *(const float4*)&A[arow + kg];
            paB1 = *(const float4*)&A[arow + kg + 4];
        } else if (k2 && kg + 7 < K) {
            float2 f0 = *(const float2*)&A[arow + kg];
            float2 f1 = *(const float2*)&A[arow + kg + 2];
            float2 f2 = *(const float2*)&A[arow + kg + 4];
            float2 f3 = *(const float2*)&A[arow + kg + 6];
            paB0 = make_float4(f0.x, f0.y, f1.x, f1.y);
            paB1 = make_float4(f2.x, f2.y, f3.x, f3.y);
        } else {
            float t[8];
            #pragma unroll
            for (int e = 0; e < 8; e++) t[e] = (kg + e < K) ? A[arow + kg + e] : 0.f;
            paB0 = *(float4*)&t[0];  paB1 = *(float4*)&t[4];
        }
        pbhB = *(const bf8v*)(wrh + kg);
        pblB = *(const bf8v*)(wrl + kg);
    };
    auto stA = [&]() {                   // cvt + LDS store — vmcnt wait lands here
        float va[8];
        *(float4*)&va[0] = paA0;  *(float4*)&va[4] = paA1;
        bf8v h0, l0;
        #pragma unroll
        for (int e = 0; e < 8; e++) {
            unsigned short h = f2bf(va[e]);
            h0[e] = (short)h;
            l0[e] = (short)f2bf(va[e] - bfu2f(h));
        }
        *(bf8v*)&Ash[ar][aq] = h0;
        *(bf8v*)&Asl[ar][aq] = l0;
        *(bf8v*)&Bsh[ar][aq] = pbhA;
        *(bf8v*)&Bsl[ar][aq] = pblA;
    };
    auto stB = [&]() {
        float va[8];
        *(float4*)&va[0] = paB0;  *(float4*)&va[4] = paB1;
        bf8v h0, l0;
        #pragma unroll
        for (int e = 0; e < 8; e++) {
            unsigned short h = f2bf(va[e]);
            h0[e] = (short)h;
            l0[e] = (short)f2bf(va[e] - bfu2f(h));
        }
        *(bf8v*)&Ash[ar][aq] = h0;
        *(bf8v*)&Asl[ar][aq] = l0;
        *(bf8v*)&Bsh[ar][aq] = pbhB;
        *(bf8v*)&Bsl[ar][aq] = pblB;
    };

    const int nt = (K + 63) >> 6;
    ldA(0);
    if (nt > 1) ldB(64);
    for (int t = 0; t < nt; t++) {
        __syncthreads();    // previous tile's fragment reads complete
        if ((t & 1) == 0) stA(); else stB();
        __syncthreads();
        int kn = (t + 2) << 6;
        if (kn < K) {       // refill the set just consumed: 2-tile lookahead
            if ((t & 1) == 0) ldA(kn); else ldB(kn);
        }
        #pragma unroll
        for (int ks = 0; ks < 2; ks++) {
            int kb = ks * 32 + lg * 8;
            bf8v a0h = *(const bf8v*)&Ash[wr * 32 + lr][kb];
            bf8v a1h = *(const bf8v*)&Ash[wr * 32 + 16 + lr][kb];
            bf8v a0l = *(const bf8v*)&Asl[wr * 32 + lr][kb];
            bf8v a1l = *(const bf8v*)&Asl[wr * 32 + 16 + lr][kb];
            bf8v b0h = *(const bf8v*)&Bsh[wc * 16 + lr][kb];
            bf8v b0l = *(const bf8v*)&Bsl[wc * 16 + lr][kb];
            acc0 = __builtin_amdgcn_mfma_f32_16x16x32_bf16(a0l, b0h, acc0, 0, 0, 0);
            acc0 = __builtin_amdgcn_mfma_f32_16x16x32_bf16(a0h, b0l, acc0, 0, 0, 0);
            acc0 = __builtin_amdgcn_mfma_f32_16x16x32_bf16(a0h, b0h, acc0, 0, 0, 0);
            acc1 = __builtin_amdgcn_mfma_f32_16x16x32_bf16(a1l, b0h, acc1, 0, 0, 0);
            acc1 = __builtin_amdgcn_mfma_f32_16x16x32_bf16(a1h, b0l, acc1, 0, 0, 0);
            acc1 = __builtin_amdgcn_mfma_f32_16x16x32_bf16(a1h, b0h, acc1, 0, 0, 0);
        }
    }

    // epilogue: C row = rb + lg*4 + g (+16), col = cb + lr  [m89 layout]
    const int isbf = *flag;
    const int rb = by * 64 + wr * 32, cb = bx * 64 + wc * 16;
    {
        int col = cb + lr;
        float bv = bias ? ldw(bias, col, isbf) : 0.f;
        float rv = radd ? radd[col] : 0.f;
        #pragma unroll
        for (int g = 0; g < 4; g++) {
            int row = rb + lg * 4 + g;
            float v = acc0[g] * (rs ? rs[row] : 1.f) + bv
                    + rv * (rsc ? rsc[row] : 1.f);
            if (relu) v = fmaxf(v, 0.f);
            C[(long)row * N + col] = v;
        }
        #pragma unroll
        for (int g = 0; g < 4; g++) {
            int row = rb + 16 + lg * 4 + g;
            float v = acc1[g] * (rs ? rs[row] : 1.f) + bv
                    + rv * (rsc ? rsc[row] : 1.f);
            if (relu) v = fmaxf(v, 0.f);
            C[(long)row * N + col] = v;
        }
    }
}

// ---------------------------------------------------------------- CSR aggregation
// out[d] = relu( dinv[d]*(t[d] + sum_{s in adj(d)} t[s]) + bias ), t prescaled by dinv
// neighbor loop unrolled x4: batch idx loads then 4 independent float4 loads (MLP)
__global__ __launch_bounds__(256) void k_aggr(const float* __restrict__ t,
    const int* __restrict__ offs, const int* __restrict__ bkt,
    const float* __restrict__ dinv, const void* __restrict__ bias,
    float* __restrict__ out, int n, int C, int relu, const int* __restrict__ flag)
{
    const int G = C >> 2;
    long i = blockIdx.x * 256L + threadIdx.x;
    if (i >= (long)n * G) return;
    int d = (int)(i / G), g = (int)(i % G);
    const float4* t4 = (const float4*)t;
    float4 acc = t4[(long)d * G + g];
    int o0 = offs[d], o1 = offs[d + 1];
    int j = o0;
    for (; j + 3 < o1; j += 4) {
        int s0 = bkt[j], s1 = bkt[j + 1], s2 = bkt[j + 2], s3 = bkt[j + 3];
        float4 v0 = t4[(long)s0 * G + g];
        float4 v1 = t4[(long)s1 * G + g];
        float4 v2 = t4[(long)s2 * G + g];
        float4 v3 = t4[(long)s3 * G + g];
        acc.x += v0.x; acc.y += v0.y; acc.z += v0.z; acc.w += v0.w;
        acc.x += v1.x; acc.y += v1.y; acc.z += v1.z; acc.w += v1.w;
        acc.x += v2.x; acc.y += v2.y; acc.z += v2.z; acc.w += v2.w;
        acc.x += v3.x; acc.y += v3.y; acc.z += v3.z; acc.w += v3.w;
    }
    for (; j < o1; j++) {
        int s = bkt[j];
        float4 v = t4[(long)s * G + g];
        acc.x += v.x; acc.y += v.y; acc.z += v.z; acc.w += v.w;
    }
    float dd = dinv[d];
    acc.x *= dd; acc.y *= dd; acc.z *= dd; acc.w *= dd;
    if (bias) {
        int isbf = *flag; int c = g << 2;
        acc.x += ldw(bias, c, isbf); acc.y += ldw(bias, c + 1, isbf);
        acc.z += ldw(bias, c + 2, isbf); acc.w += ldw(bias, c + 3, isbf);
    }
    if (relu) {
        acc.x = fmaxf(acc.x, 0.f); acc.y = fmaxf(acc.y, 0.f);
        acc.z = fmaxf(acc.z, 0.f); acc.w = fmaxf(acc.w, 0.f);
    }
    ((float4*)out)[(long)d * G + g] = acc;
}

// sigma = Ahat @ 1
__global__ void k_sigacc(const int* __restrict__ src, const int* __restrict__ dst,
                         const float* __restrict__ dinv, float* __restrict__ sig, int E) {
    int e = blockIdx.x * 256 + threadIdx.x;
    if (e < E) atomicAdd(&sig[dst[e]], dinv[src[e]]);
}
__global__ void k_sigfin(float* __restrict__ sig, const float* __restrict__ dinv, int n) {
    int i = blockIdx.x * 256 + threadIdx.x;
    if (i < n) sig[i] = dinv[i] * (sig[i] + dinv[i]);
}
__global__ void k_rowvec_acc(const float* __restrict__ gmax, const void* __restrict__ W,
                             float* __restrict__ out, const int* __restrict__ flag) {
    int n = blockIdx.x * 256 + threadIdx.x;
    if (n >= 1024) return;
    const int isbf = *flag;
    int c0 = blockIdx.y * 128;
    float s = 0.f;
    for (int c = c0; c < c0 + 128; c++) s += gmax[c] * ldw(W, (long)c * 1024 + n, isbf);
    atomicAdd(&out[n], s);
}

// ---------------------------------------------------------------- batchnorm + relu (n<=1024)
__global__ __launch_bounds__(256) void k_bn(float* __restrict__ h, const void* __restrict__ gamma,
                                            const void* __restrict__ beta, int n, int C,
                                            const int* __restrict__ flag) {
    int c = blockIdx.x;
    int tid = threadIdx.x;
    __shared__ float sm[256];
    float v[4];
    float s = 0.f;
    #pragma unroll
    for (int u = 0; u < 4; u++) {
        int r = tid + u * 256;
        v[u] = (r < n) ? h[(long)r * C + c] : 0.f;
        s += v[u];
    }
    sm[tid] = s; __syncthreads();
    for (int o = 128; o > 0; o >>= 1) { if (tid < o) sm[tid] += sm[tid + o]; __syncthreads(); }
    float mu = sm[0] / n;
    __syncthreads();
    float s2 = 0.f;
    #pragma unroll
    for (int u = 0; u < 4; u++) {
        int r = tid + u * 256;
        if (r < n) { float d = v[u] - mu; s2 += d * d; }
    }
    sm[tid] = s2; __syncthreads();
    for (int o = 128; o > 0; o >>= 1) { if (tid < o) sm[tid] += sm[tid + o]; __syncthreads(); }
    float var = sm[0] / n;
    float rsq = rsqrtf(var + 1e-5f);
    float g = ldw(gamma, c, *flag), be = ldw(beta, c, *flag);
    #pragma unroll
    for (int u = 0; u < 4; u++) {
        int r = tid + u * 256;
        if (r < n) h[(long)r * C + c] = fmaxf((v[u] - mu) * rsq * g + be, 0.f);
    }
}

// column max of h(1024 x 2048): 32 blocks x 64 cols
__global__ __launch_bounds__(256) void k_cmax(const float* __restrict__ h, float* __restrict__ out) {
    __shared__ float sm[256];
    int coff = threadIdx.x & 63, rq = threadIdx.x >> 6;
    int c = blockIdx.x * 64 + coff;
    float m = -3.0e38f;
    for (int r = rq; r < 1024; r += 4) m = fmaxf(m, h[(long)r * 2048 + c]);
    sm[threadIdx.x] = m;
    __syncthreads();
    if (rq == 0) {
        m = fmaxf(fmaxf(sm[coff], sm[64 + coff]), fmaxf(sm[128 + coff], sm[192 + coff]));
        out[c] = m;
    }
}

// ---------------------------------------------------------------- gather / strided copy
__global__ void k_gather(const float* __restrict__ src, const int* __restrict__ idx,
                         float* __restrict__ dst, int n, int ncol, int ss, int ds, int doff) {
    long i = blockIdx.x * 256L + threadIdx.x;
    if (i < (long)n * ncol) {
        int r = (int)(i / ncol), c = (int)(i % ncol);
        dst[(long)r * ds + doff + c] = src[(long)idx[r] * ss + c];
    }
}
// copy with optional per-row scale (rmul may be nullptr)
__global__ void k_copy(const float* __restrict__ src, float* __restrict__ dst,
                       const float* __restrict__ rmul,
                       int n, int ncol, int ss, int ds, int doff) {
    long i = blockIdx.x * 256L + threadIdx.x;
    if (i < (long)n * ncol) {
        int r = (int)(i / ncol), c = (int)(i % ncol);
        float v = src[(long)r * ss + c];
        if (rmul) v *= rmul[r];
        dst[(long)r * ds + doff + c] = v;
    }
}

// ---------------------------------------------------------------- kNN (k=3), one wave per dst
// psrc packed as float4 (x,y,z,|p|^2); compare on r = ns - 2*dot (== d2 - nd).
// NOTE: top-3 insert is straight-line macro code — a by-reference lambda here
// spilled all state to scratch (VGPR 16->12, WRITE_SIZE 0.5->6.5MB, 2.4x slower).
__device__ __forceinline__ bool knn_better(float d, int i, float D, int I) {
    return d < D || (d == D && i < I);
}
#define KNN_INS(rv, sv)                                                              \
    if ((rv) < bd2) {                                                                \
        if ((rv) < bd0)      { bd2 = bd1; bi2 = bi1; bd1 = bd0; bi1 = bi0;           \
                               bd0 = (rv); bi0 = (sv); }                             \
        else if ((rv) < bd1) { bd2 = bd1; bi2 = bi1; bd1 = (rv); bi1 = (sv); }       \
        else                 { bd2 = (rv); bi2 = (sv); }                             \
    }
__global__ __launch_bounds__(256) void k_knn_w(const float* __restrict__ pdst,
                                               const float4* __restrict__ psrc4,
                                               int M, int Ns,
                                               int* __restrict__ kidx, float* __restrict__ kw) {
    int wid = (blockIdx.x * 256 + threadIdx.x) >> 6;
    int lane = threadIdx.x & 63;
    if (wid >= M) return;
    float x = pdst[wid * 3], y = pdst[wid * 3 + 1], z = pdst[wid * 3 + 2];
    float nd = fmaf(x, x, fmaf(y, y, z * z));
    float bd0 = 3.4e38f, bd1 = 3.4e38f, bd2 = 3.4e38f;
    int bi0 = 0x7fffffff, bi1 = 0x7fffffff, bi2 = 0x7fffffff;
    int s = lane;
    for (; s + 64 < Ns; s += 128) {
        float4 q0 = psrc4[s];
        float4 q1 = psrc4[s + 64];
        float r0 = fmaf(-2.f, fmaf(x, q0.x, fmaf(y, q0.y, z * q0.z)), q0.w);
        float r1 = fmaf(-2.f, fmaf(x, q1.x, fmaf(y, q1.y, z * q1.z)), q1.w);
        KNN_INS(r0, s);
        KNN_INS(r1, s + 64);
    }
    for (; s < Ns; s += 64) {
        float4 q = psrc4[s];
        float r = fmaf(-2.f, fmaf(x, q.x, fmaf(y, q.y, z * q.z)), q.w);
        KNN_INS(r, s);
    }
    #pragma unroll
    for (int off = 32; off >= 1; off >>= 1) {
        float od0 = __shfl_xor(bd0, off, 64); int oi0 = __shfl_xor(bi0, off, 64);
        float od1 = __shfl_xor(bd1, off, 64); int oi1 = __shfl_xor(bi1, off, 64);
        float od2 = __shfl_xor(bd2, off, 64); int oi2 = __shfl_xor(bi2, off, 64);
        float dq[3] = {od0, od1, od2}; int iq[3] = {oi0, oi1, oi2};
        #pragma unroll
        for (int q = 0; q < 3; q++) {
            float dd = dq[q]; int ii = iq[q];
            if (knn_better(dd, ii, bd0, bi0))      { bd2 = bd1; bi2 = bi1; bd1 = bd0; bi1 = bi0; bd0 = dd; bi0 = ii; }
            else if (knn_better(dd, ii, bd1, bi1)) { bd2 = bd1; bi2 = bi1; bd1 = dd; bi1 = ii; }
            else if (knn_better(dd, ii, bd2, bi2)) { bd2 = dd; bi2 = ii; }
        }
    }
    if (lane == 0) {
        kidx[wid * 3] = bi0; kidx[wid * 3 + 1] = bi1; kidx[wid * 3 + 2] = bi2;
        kw[wid * 3]     = 1.0f / fmaxf(nd + bd0, 1e-16f);
        kw[wid * 3 + 1] = 1.0f / fmaxf(nd + bd1, 1e-16f);
        kw[wid * 3 + 2] = 1.0f / fmaxf(nd + bd2, 1e-16f);
    }
}

__global__ void k_knn_apply4(const float* __restrict__ h, const int* __restrict__ kidx,
                             const float* __restrict__ kw, const float* __restrict__ rmul,
                             float* __restrict__ out,
                             int M, int C, int ds) {  // C%4==0, ds%4==0
    const int G = C >> 2;
    long i = blockIdx.x * 256L + threadIdx.x;
    if (i >= (long)M * G) return;
    int r = (int)(i / G), g = (int)(i % G);
    int i0 = kidx[r * 3], i1 = kidx[r * 3 + 1], i2 = kidx[r * 3 + 2];
    float w0 = kw[r * 3], w1 = kw[r * 3 + 1], w2 = kw[r * 3 + 2];
    float inv = 1.0f / (w0 + w1 + w2);
    const float4* h4 = (const float4*)h;
    float4 a = h4[(long)i0 * G + g], b = h4[(long)i1 * G + g], c = h4[(long)i2 * G + g];
    float4 o;
    o.x = (w0 * a.x + w1 * b.x + w2 * c.x) * inv;
    o.y = (w0 * a.y + w1 * b.y + w2 * c.y) * inv;
    o.z = (w0 * a.z + w1 * b.z + w2 * c.z) * inv;
    o.w = (w0 * a.w + w1 * b.w + w2 * c.w) * inv;
    if (rmul) {
        float dd = rmul[r];
        o.x *= dd; o.y *= dd; o.z *= dd; o.w *= dd;
    }
    *(float4*)&out[(long)r * ds + (g << 2)] = o;
}
__global__ void k_knn_apply2(const float* __restrict__ h, const int* __restrict__ kidx,
                             const float* __restrict__ kw, float* __restrict__ out,
                             int M, int C, int ds) {  // C%2==0, ds%2==0
    const int G = C >> 1;
    long i = blockIdx.x * 256L + threadIdx.x;
    if (i >= (long)M * G) return;
    int r = (int)(i / G), g = (int)(i % G);
    int i0 = kidx[r * 3], i1 = kidx[r * 3 + 1], i2 = kidx[r * 3 + 2];
    float w0 = kw[r * 3], w1 = kw[r * 3 + 1], w2 = kw[r * 3 + 2];
    float inv = 1.0f / (w0 + w1 + w2);
    const float2* h2 = (const float2*)h;
    float2 a = h2[(long)i0 * G + g], b = h2[(long)i1 * G + g], c = h2[(long)i2 * G + g];
    float2 o;
    o.x = (w0 * a.x + w1 * b.x + w2 * c.x) * inv;
    o.y = (w0 * a.y + w1 * b.y + w2 * c.y) * inv;
    *(float2*)&out[(long)r * ds + (g << 1)] = o;
}

// ---------------------------------------------------------------- launch
extern "C" void kernel_launch(void* const* d_in, const int* in_sizes, int n_in,
                              void* d_out, int out_size, void* d_ws, size_t ws_size,
                              hipStream_t stream) {
    const int N0 = 16384, N1 = 4096, N2 = 1024;
    const int E0 = in_sizes[48] / 2, E1 = in_sizes[49] / 2, E2 = in_sizes[50] / 2;

    const int* idx0 = (const int*)d_in[46];
    const int* idx1 = (const int*)d_in[47];
    const int* ei0  = (const int*)d_in[48];
    const int* ei1  = (const int*)d_in[49];
    const int* ei2  = (const int*)d_in[50];

    float* W = (float*)d_ws;
    size_t off = 0;
    auto alloc = [&](size_t nf) { float* p = W + off; off += (nf + 63) & ~(size_t)63; return p; };
    auto allocU = [&](size_t nu) { return (unsigned short*)alloc((nu + 1) / 2); };
    float* P     = alloc(4194304);   // 16384x256 == 4096x1024 == 1024x2048(+)
    float* Q     = alloc(4194304);
    float* CAT   = alloc(8486912);   // 16384x518 >= 16384x256 >= 4096x320
    float* xf    = alloc(98304);     // 16384x6 (also final 16384x4 out)
    float* posf  = alloc(49152);
    float* pos1  = alloc(12288);
    float* pos2  = alloc(3072);
    float* pos1p = alloc(16384);     // 4096 float4 packed
    float* pos2p = alloc(4096);      // 1024 float4 packed
    float* dinv0 = alloc(16384);
    float* dinv1 = alloc(4096);
    float* dinv2 = alloc(1024);
    float* x1    = alloc(262144);    // 4096x64
    float* c2    = alloc(134144);    // 1024x131
    float* xb    = alloc(262144);    // 1024x256
    float* gmaxb = alloc(2048);
    float* rowv  = alloc(1024);
    float* sigb  = alloc(4096);
    float* kwb   = alloc(49152);
    int*   kib   = (int*)alloc(49152);
    int*   flg   = (int*)alloc(64);
    int*   cntb  = (int*)alloc(16384);
    int*   offs0 = (int*)alloc(16448);
    int*   offs1 = (int*)alloc(4160);
    int*   offs2 = (int*)alloc(1088);
    int*   bkt0  = (int*)alloc(E0);
    int*   bkt1  = (int*)alloc(E1);
    int*   bkt2  = (int*)alloc(E2);

    // bf16 W^T hi/lo planes (N x Kpad each) — appended last; guard below disables
    // the MFMA path entirely if they don't fit in ws.
    struct WtPair { unsigned short *h, *l; int Kp; };
    auto mkwt = [&](size_t n, int Kp) {
        WtPair p; p.h = allocU(n); p.l = allocU(n); p.Kp = Kp; return p;
    };
    WtPair wt6  = mkwt(64 * 64, 64);
    WtPair wt8  = mkwt(64 * 128, 128);
    WtPair wt10 = mkwt(64 * 64, 64);
    WtPair wt12 = mkwt(128 * 64, 64);
    WtPair wt14 = mkwt(128 * 192, 192);
    WtPair wt16 = mkwt(128 * 128, 128);
    WtPair wt18 = mkwt(256 * 128, 128);
    WtPair wt20 = mkwt(512 * 192, 192);
    WtPair wt22 = mkwt(1024 * 512, 512);
    WtPair wt24 = mkwt(2048 * 1024, 1024);
    WtPair wt30 = mkwt(1024 * 320, 320);
    WtPair wt32 = mkwt(1024 * 1024, 1024);
    WtPair wt34 = mkwt(512 * 1024, 1024);
    WtPair wt36 = mkwt(256 * 576, 576);
    WtPair wt38 = mkwt(256 * 256, 256);
    WtPair wt40 = mkwt(128 * 256, 256);
    WtPair wt42 = mkwt(64 * 128, 128);

    const bool usex = (off * sizeof(float)) <= ws_size;

    auto g1 = [](long n) { return dim3((unsigned)((n + 255) / 256)); };

    auto mm = [&](const float* Ain, int iw, int ib, const float* radd, const float* rsc,
                  const float* rs, float* out, int M_, int K_, int N_, long woff, int relu) {
        dim3 g((N_ + 63) / 64, M_ / 64);
        k_mm<<<g, 256, 0, stream>>>(Ain, d_in[iw], ib >= 0 ? d_in[ib] : nullptr,
                                    radd, rsc, rs, out, M_, K_, N_, woff, relu, flg);
    };
    auto mmx = [&](const float* Ain, int iw, int ib, const float* radd, const float* rsc,
                   const float* rs, float* out, int M_, int K_, int N_, long woff, int relu,
                   const WtPair& wp) {
        if (usex) {
            dim3 g(N_ / 64, M_ / 64);
            k_mmx<<<g, 512, 0, stream>>>(Ain, wp.h, wp.l,
                                         ib >= 0 ? d_in[ib] : nullptr,
                                         radd, rsc, rs, out, M_, K_, wp.Kp, N_, relu, flg);
        } else {
            mm(Ain, iw, ib, radd, rsc, rs, out, M_, K_, N_, woff, relu);
        }
    };
    auto gcnx = [&](const float* Ain, int n, int K, int iw, int ib, int C,
                    const int* offs, const int* bkt, const float* dinv, float* t, float* out,
                    const WtPair& wp) {
        mmx(Ain, iw, -1, nullptr, nullptr, dinv, t, n, K, C, 0, 0, wp);
        k_aggr<<<g1((long)n * (C >> 2)), 256, 0, stream>>>(t, offs, bkt, dinv, d_in[ib],
                                                           out, n, C, 1, flg);
    };
    auto gcn = [&](const float* Ain, int n, int K, int iw, int ib, int C,
                   const int* offs, const int* bkt, const float* dinv, float* t, float* out) {
        mm(Ain, iw, -1, nullptr, nullptr, dinv, t, n, K, C, 0, 0);
        k_aggr<<<g1((long)n * (C >> 2)), 256, 0, stream>>>(t, offs, bkt, dinv, d_in[ib],
                                                           out, n, C, 1, flg);
    };
    auto csr = [&](const int* ei, int E, int n, int* offs, int* bkt, float* dinv) {
        k_zero_i<<<g1(n), 256, 0, stream>>>(cntb, n);
        k_count<<<g1(E), 256, 0, stream>>>(ei + E, cntb, E);
        k_dinv_i<<<g1(n), 256, 0, stream>>>(cntb, dinv, n);
        k_scan<<<1, 1024, 0, stream>>>(cntb, offs, n);
        k_zero_i<<<g1(n), 256, 0, stream>>>(cntb, n);
        k_fill<<<g1(E), 256, 0, stream>>>(ei, ei + E, offs, cntb, bkt, E);
    };
    auto wtk = [&](int iw, long woff, int K_, int N_, const WtPair& wp) {
        if (!usex) return;
        dim3 g(N_ / 32, wp.Kp / 32);
        k_wt<<<g, 256, 0, stream>>>(d_in[iw], woff, wp.h, wp.l, K_, N_, wp.Kp, flg);
    };

    // dtype detection + input conversion + CSR + weight transposes
    k_detect<<<1, 256, 0, stream>>>((const unsigned short*)d_in[2], in_sizes[2], flg);
    k_cvt_in<<<g1(N0 * 6), 256, 0, stream>>>(d_in[0], xf, N0 * 6, flg);
    k_cvt_in<<<g1(N0 * 3), 256, 0, stream>>>(d_in[1], posf, N0 * 3, flg);
    csr(ei0, E0, N0, offs0, bkt0, dinv0);
    csr(ei1, E1, N1, offs1, bkt1, dinv1);
    csr(ei2, E2, N2, offs2, bkt2, dinv2);
    wtk(6, 0, 32, 64, wt6);
    wtk(8, 0, 67, 64, wt8);
    wtk(10, 0, 64, 64, wt10);
    wtk(12, 0, 64, 128, wt12);
    wtk(14, 0, 131, 128, wt14);
    wtk(16, 0, 128, 128, wt16);
    wtk(18, 0, 128, 256, wt18);
    wtk(20, 0, 131, 512, wt20);
    wtk(22, 0, 512, 1024, wt22);
    wtk(24, 0, 1024, 2048, wt24);
    wtk(30, 2048L * 1024L, 320, 1024, wt30);
    wtk(32, 0, 1024, 1024, wt32);
    wtk(34, 0, 1024, 512, wt34);
    wtk(36, 0, 518, 256, wt36);
    wtk(38, 0, 256, 256, wt38);
    wtk(40, 0, 256, 128, wt40);
    wtk(42, 0, 128, 64, wt42);

    // SA1: 6->32->32->64 on level-0 graph  (N=32 layers stay fp32)
    gcn(xf, N0, 6, 2, 3, 32, offs0, bkt0, dinv0, P, Q);
    gcn(Q, N0, 32, 4, 5, 32, offs0, bkt0, dinv0, P, Q);
    gcnx(Q, N0, 32, 6, 7, 64, offs0, bkt0, dinv0, P, Q, wt6);
    k_gather<<<g1((long)N1 * 64), 256, 0, stream>>>(Q, idx0, x1, N1, 64, 64, 64, 0);
    k_gather<<<g1((long)N1 * 3), 256, 0, stream>>>(posf, idx0, pos1, N1, 3, 3, 3, 0);

    // SA2: [x1|pos1](67) -> 64->64->128 on level-1 graph
    k_copy<<<g1((long)N1 * 64), 256, 0, stream>>>(x1, P, nullptr, N1, 64, 64, 67, 0);
    k_copy<<<g1((long)N1 * 3), 256, 0, stream>>>(pos1, P, nullptr, N1, 3, 3, 67, 64);
    gcnx(P, N1, 67, 8, 9, 64, offs1, bkt1, dinv1, Q, P, wt8);
    gcnx(P, N1, 64, 10, 11, 64, offs1, bkt1, dinv1, Q, P, wt10);
    gcnx(P, N1, 64, 12, 13, 128, offs1, bkt1, dinv1, Q, P, wt12);
    k_gather<<<g1((long)N2 * 128), 256, 0, stream>>>(P, idx1, c2, N2, 128, 128, 131, 0);
    k_gather<<<g1((long)N2 * 3), 256, 0, stream>>>(pos1, idx1, pos2, N2, 3, 3, 3, 0);
    k_copy<<<g1((long)N2 * 3), 256, 0, stream>>>(pos2, c2, nullptr, N2, 3, 3, 131, 128);

    // bottleneck: 131 -> 128->128->256 on level-2 graph
    gcnx(c2, N2, 131, 14, 15, 128, offs2, bkt2, dinv2, P, Q, wt14);
    gcnx(Q, N2, 128, 16, 17, 128, offs2, bkt2, dinv2, P, Q, wt16);
    gcnx(Q, N2, 128, 18, 19, 256, offs2, bkt2, dinv2, P, xb, wt18);

    // GlobalSA
    mmx(c2, 20, 21, nullptr, nullptr, nullptr, P, N2, 131, 512, 0, 0, wt20);
    k_bn<<<dim3(512), 256, 0, stream>>>(P, d_in[26], d_in[27], N2, 512, flg);
    mmx(P, 22, 23, nullptr, nullptr, nullptr, Q, N2, 512, 1024, 0, 0, wt22);
    k_bn<<<dim3(1024), 256, 0, stream>>>(Q, d_in[28], d_in[29], N2, 1024, flg);
    mmx(Q, 24, 25, nullptr, nullptr, nullptr, P, N2, 1024, 2048, 0, 0, wt24);
    k_cmax<<<dim3(32), 256, 0, stream>>>(P, gmaxb);

    // FP2: out1 = relu( (Ahat [interp(xb)|x1]) @ W[2048:] + sigma*rowv + b )
    k_zero<<<g1(1024), 256, 0, stream>>>(rowv, 1024);
    k_rowvec_acc<<<dim3(4, 16), 256, 0, stream>>>(gmaxb, d_in[30], rowv, flg);
    k_pack4<<<g1(N1), 256, 0, stream>>>(pos1, (float4*)pos1p, N1);
    k_pack4<<<g1(N2), 256, 0, stream>>>(pos2, (float4*)pos2p, N2);
    k_knn_w<<<g1((long)N1 * 64), 256, 0, stream>>>(pos1, (const float4*)pos2p, N1, N2, kib, kwb);
    k_knn_apply4<<<g1((long)N1 * 64), 256, 0, stream>>>(xb, kib, kwb, dinv1, CAT, N1, 256, 320);
    k_copy<<<g1((long)N1 * 64), 256, 0, stream>>>(x1, CAT, dinv1, N1, 64, 64, 320, 256);
    k_aggr<<<g1((long)N1 * 80), 256, 0, stream>>>(CAT, offs1, bkt1, dinv1, nullptr,
                                                  P, N1, 320, 0, flg);
    k_zero<<<g1(N1), 256, 0, stream>>>(sigb, N1);
    k_sigacc<<<g1(E1), 256, 0, stream>>>(ei1, ei1 + E1, dinv1, sigb, E1);
    k_sigfin<<<g1(N1), 256, 0, stream>>>(sigb, dinv1, N1);
    mmx(P, 30, 31, rowv, sigb, nullptr, Q, N1, 320, 1024, 2048L * 1024L, 1, wt30);
    gcnx(Q, N1, 1024, 32, 33, 1024, offs1, bkt1, dinv1, P, Q, wt32);
    gcnx(Q, N1, 1024, 34, 35, 512, offs1, bkt1, dinv1, P, Q, wt34);  // Q: 4096x512

    // FP1
    k_knn_w<<<g1((long)N0 * 64), 256, 0, stream>>>(posf, (const float4*)pos1p, N0, N1, kib, kwb);
    k_knn_apply2<<<g1((long)N0 * 256), 256, 0, stream>>>(Q, kib, kwb, CAT, N0, 512, 518);
    k_copy<<<g1((long)N0 * 6), 256, 0, stream>>>(xf, CAT, nullptr, N0, 6, 6, 518, 512);
    gcnx(CAT, N0, 518, 36, 37, 256, offs0, bkt0, dinv0, P, Q, wt36);
    gcnx(Q, N0, 256, 38, 39, 256, offs0, bkt0, dinv0, P, CAT, wt38);
    gcnx(CAT, N0, 256, 40, 41, 128, offs0, bkt0, dinv0, P, Q, wt40);

    // final MLP: 128 -> 64 (relu) -> 4
    mmx(Q, 42, 43, nullptr, nullptr, nullptr, P, N0, 128, 64, 0, 1, wt42);
    mm(P, 44, 45, nullptr, nullptr, nullptr, xf, N0, 64, 4, 0, 0);
    k_out<<<g1(N0 * 4), 256, 0, stream>>>(xf, d_out, N0 * 4, flg);
}

// Round 15
// 1042.537 us; speedup vs baseline: 1.0191x; 1.0191x over previous
//
#include <hip/hip_runtime.h>
#include <hip/hip_bf16.h>

typedef __hip_bfloat16 bf16;
typedef __attribute__((ext_vector_type(8))) short bf8v;   // 8 bf16 (4 VGPR)
typedef __attribute__((ext_vector_type(4))) float f32x4;  // MFMA acc

// flag: 1 = float tensors are bf16, 0 = fp32
__device__ __forceinline__ float ldw(const void* p, long i, int isbf) {
    return isbf ? __bfloat162float(((const bf16*)p)[i]) : ((const float*)p)[i];
}
__device__ __forceinline__ unsigned short f2bf(float v) {
    bf16 h = __float2bfloat16(v);
    return *reinterpret_cast<unsigned short*>(&h);
}
__device__ __forceinline__ float bfu2f(unsigned short u) {
    return __uint_as_float((unsigned)u << 16);
}

// ---------------------------------------------------------------- dtype detect
__global__ void k_detect(const unsigned short* __restrict__ w, int n, int* __restrict__ flag) {
    __shared__ int cnt;
    if (threadIdx.x == 0) cnt = 0;
    __syncthreads();
    int bad = 0;
    for (int i = threadIdx.x; i < n; i += 256) {
        int e = (w[i] >> 7) & 0xFF;
        if (e == 0xFF || (e != 0 && (e < 64 || e > 190))) bad++;
    }
    atomicAdd(&cnt, bad);
    __syncthreads();
    if (threadIdx.x == 0) *flag = (cnt > n / 16) ? 0 : 1;
}

// ---------------------------------------------------------------- small utils
__global__ void k_cvt_in(const void* __restrict__ s, float* __restrict__ d, int n,
                         const int* __restrict__ flag) {
    int i = blockIdx.x * 256 + threadIdx.x;
    if (i < n) d[i] = ldw(s, i, *flag);
}
__global__ void k_out(const float* __restrict__ s, void* __restrict__ d, int n,
                      const int* __restrict__ flag) {
    int i = blockIdx.x * 256 + threadIdx.x;
    if (i < n) {
        if (*flag) ((bf16*)d)[i] = __float2bfloat16(s[i]);
        else       ((float*)d)[i] = s[i];
    }
}
__global__ void k_zero(float* __restrict__ d, int n) {
    int i = blockIdx.x * 256 + threadIdx.x;
    if (i < n) d[i] = 0.f;
}
__global__ void k_zero_i(int* __restrict__ d, int n) {
    int i = blockIdx.x * 256 + threadIdx.x;
    if (i < n) d[i] = 0;
}
// pack (x,y,z) triplets -> float4 (x,y,z,|p|^2)
__global__ void k_pack4(const float* __restrict__ p, float4* __restrict__ o, int n) {
    int i = blockIdx.x * 256 + threadIdx.x;
    if (i < n) {
        float x = p[3 * i], y = p[3 * i + 1], z = p[3 * i + 2];
        float4 v = {x, y, z, fmaf(x, x, fmaf(y, y, z * z))};
        o[i] = v;
    }
}

// ---------------------------------------------------------------- CSR build
__global__ void k_count(const int* __restrict__ dst, int* __restrict__ cnt, int E) {
    int i = blockIdx.x * 256 + threadIdx.x;
    if (i < E) atomicAdd(&cnt[dst[i]], 1);
}
__global__ void k_dinv_i(const int* __restrict__ cnt, float* __restrict__ dinv, int n) {
    int i = blockIdx.x * 256 + threadIdx.x;
    if (i < n) dinv[i] = rsqrtf((float)cnt[i] + 1.0f);  // +1 self loop
}
// single block, 1024 threads, exclusive scan of cnt[0..n) -> offs, offs[n]=E
__global__ __launch_bounds__(1024) void k_scan(const int* __restrict__ cnt,
                                               int* __restrict__ offs, int n) {
    __shared__ int sm[1024];
    int t = threadIdx.x;
    int chunk = (n + 1023) >> 10;
    int b0 = t * chunk, b1 = min(b0 + chunk, n);
    int s = 0;
    for (int i = b0; i < b1; i++) s += cnt[i];
    sm[t] = s;
    __syncthreads();
    for (int o = 1; o < 1024; o <<= 1) {
        int v = (t >= o) ? sm[t - o] : 0;
        __syncthreads();
        sm[t] += v;
        __syncthreads();
    }
    int run = sm[t] - s;  // exclusive
    for (int i = b0; i < b1; i++) { offs[i] = run; run += cnt[i]; }
    if (t == 1023) offs[n] = sm[1023];
}
__global__ void k_fill(const int* __restrict__ src, const int* __restrict__ dst,
                       const int* __restrict__ offs, int* __restrict__ cur,
                       int* __restrict__ bkt, int E) {
    int e = blockIdx.x * 256 + threadIdx.x;
    if (e < E) {
        int d = dst[e];
        int p = atomicAdd(&cur[d], 1);
        bkt[offs[d] + p] = src[e];
    }
}

// ---------------------------------------------------------------- weight transpose + hi/lo split
// W (KxN, flagged dtype, offset woff) -> WTh/WTl (N x Kpad bf16), zero-pad k>=K
// grid (N/32, Kpad/32), 256 threads
__global__ __launch_bounds__(256) void k_wt(const void* __restrict__ W, long woff,
                                            unsigned short* __restrict__ WTh,
                                            unsigned short* __restrict__ WTl,
                                            int K, int N, int Kpad,
                                            const int* __restrict__ flag) {
    __shared__ unsigned short th[32][33];
    __shared__ unsigned short tl[32][33];
    const int isbf = *flag;
    int n0 = blockIdx.x * 32, k0 = blockIdx.y * 32;
    int c = threadIdx.x & 31, r = threadIdx.x >> 5;   // r 0..7
    #pragma unroll
    for (int u = 0; u < 4; u++) {
        int k = k0 + r + u * 8;
        float v = (k < K) ? ldw(W, woff + (long)k * N + n0 + c, isbf) : 0.f;
        unsigned short h = f2bf(v);
        th[r + u * 8][c] = h;
        tl[r + u * 8][c] = f2bf(v - bfu2f(h));
    }
    __syncthreads();
    #pragma unroll
    for (int u = 0; u < 4; u++) {
        int n = n0 + r + u * 8;
        WTh[(long)n * Kpad + k0 + c] = th[c][r + u * 8];
        WTl[(long)n * Kpad + k0 + c] = tl[c][r + u * 8];
    }
}

// ---------------------------------------------------------------- matmul (fp32, generic)
__global__ __launch_bounds__(256) void k_mm(
    const float* __restrict__ A, const void* __restrict__ Wt,
    const void* __restrict__ bias, const float* __restrict__ radd,
    const float* __restrict__ rsc, const float* __restrict__ rs,
    float* __restrict__ C, int M, int K, int N, long woff, int relu,
    const int* __restrict__ flag)
{
    __shared__ float As[2][16][68];
    __shared__ float Bs[2][16][68];
    const int isbf = *flag;
    const int tid = threadIdx.x;
    const int tx = tid & 15, ty = tid >> 4;
    const int bx = blockIdx.x, by = blockIdx.y;

    const int ar = tid >> 2, aq = (tid & 3) << 2;
    const long arow = (long)(by * 64 + ar) * K;
    const int bkk = tid >> 4, bn4 = (tid & 15) << 2;
    const int bcol0 = bx * 64 + bn4;

    float acc[4][4] = {};
    float4 pa, pb;

    auto loadAB = [&](int k0) {
        int kg = k0 + aq;
        pa.x = (kg + 0 < K) ? A[arow + kg + 0] : 0.f;
        pa.y = (kg + 1 < K) ? A[arow + kg + 1] : 0.f;
        pa.z = (kg + 2 < K) ? A[arow + kg + 2] : 0.f;
        pa.w = (kg + 3 < K) ? A[arow + kg + 3] : 0.f;
        int kb = k0 + bkk;
        pb = make_float4(0.f, 0.f, 0.f, 0.f);
        if (kb < K) {
            long base = woff + (long)kb * N + bcol0;
            if (bcol0 + 3 < N) {
                pb.x = ldw(Wt, base + 0, isbf); pb.y = ldw(Wt, base + 1, isbf);
                pb.z = ldw(Wt, base + 2, isbf); pb.w = ldw(Wt, base + 3, isbf);
            } else {
                if (bcol0 < N)     pb.x = ldw(Wt, base + 0, isbf);
                if (bcol0 + 1 < N) pb.y = ldw(Wt, base + 1, isbf);
                if (bcol0 + 2 < N) pb.z = ldw(Wt, base + 2, isbf);
            }
        }
    };
    auto storeAB = [&](int b) {
        As[b][aq + 0][ar] = pa.x;  As[b][aq + 1][ar] = pa.y;
        As[b][aq + 2][ar] = pa.z;  As[b][aq + 3][ar] = pa.w;
        *(float4*)&Bs[b][bkk][bn4] = pb;
    };

    loadAB(0);
    storeAB(0);
    __syncthreads();

    const int nk = (K + 15) >> 4;
    for (int t = 0; t < nk; t++) {
        const int cur = t & 1;
        const bool more = (t + 1 < nk);
        if (more) loadAB((t + 1) << 4);
        #pragma unroll
        for (int kk = 0; kk < 16; kk++) {
            float4 a = *(const float4*)&As[cur][kk][ty << 2];
            float4 b = *(const float4*)&Bs[cur][kk][tx << 2];
            float av[4] = {a.x, a.y, a.z, a.w};
            float bv[4] = {b.x, b.y, b.z, b.w};
            #pragma unroll
            for (int i = 0; i < 4; i++)
                #pragma unroll
                for (int j = 0; j < 4; j++)
                    acc[i][j] = fmaf(av[i], bv[j], acc[i][j]);
        }
        if (more) storeAB(cur ^ 1);
        __syncthreads();
    }

    const int col = bx * 64 + (tx << 2);
    #pragma unroll
    for (int i = 0; i < 4; i++) {
        int r = by * 64 + (ty << 2) + i;
        float m = rs ? rs[r] : 1.0f;
        float rr = rsc ? rsc[r] : 1.0f;
        float v[4];
        #pragma unroll
        for (int j = 0; j < 4; j++) {
            v[j] = acc[i][j] * m;
            int c = col + j;
            if (c < N) {
                if (bias) v[j] += ldw(bias, c, isbf);
                if (radd) v[j] += radd[c] * rr;
            }
            if (relu) v[j] = fmaxf(v[j], 0.f);
        }
        if (col + 3 < N) {
            float4 o = {v[0], v[1], v[2], v[3]};
            *(float4*)&C[(long)r * N + col] = o;
        } else {
            for (int j = 0; j < 4; j++)
                if (col + j < N) C[(long)r * N + col + j] = v[j];
        }
    }
}

// ---------------------------------------------------------------- matmul (MFMA bf16x3)
// fp32 accuracy via hi/lo bf16 split: a*b ~= al*bh + ah*bl + ah*bh (fp32 accum).
// Round 15: r13 structure (512 thr, 1-deep ld/st — best known) + LDS DOUBLE
// BUFFER: ld(t+1) -> compute(buf[cur]) -> st(buf[cur^1]) -> sync. One barrier
// per tile (was two) and the cvt/store's vmcnt wait sits AFTER the compute
// phase. Lookahead stays 1 tile -> FETCH stays ~25MB (r14's 2-deep thrashed
// L2: FETCH 24.7->40.3MB, dur +31%; reverted). 73.7KB LDS -> 2 blocks/CU,
// 16 waves/CU (r13 proved occupancy >30% isn't binding). Accum order same.
__global__ __launch_bounds__(512, 4) void k_mmx(
    const float* __restrict__ A,
    const unsigned short* __restrict__ WTh, const unsigned short* __restrict__ WTl,
    const void* __restrict__ bias, const float* __restrict__ radd,
    const float* __restrict__ rsc, const float* __restrict__ rs,
    float* __restrict__ C, int M, int K, int Kpad, int N, int relu,
    const int* __restrict__ flag)
{
    __shared__ unsigned short Ash[2][64][72];
    __shared__ unsigned short Asl[2][64][72];
    __shared__ unsigned short Bsh[2][64][72];
    __shared__ unsigned short Bsl[2][64][72];
    const int tid = threadIdx.x;
    // XCD-aware swizzle (FETCH 75->19MB measured); bijective iff nwg%8==0.
    const int nbx = gridDim.x;
    int id = blockIdx.y * nbx + blockIdx.x;
    {
        int nwg = nbx * gridDim.y;
        if ((nwg & 7) == 0) {
            int xcd = id & 7, pos = id >> 3;
            id = xcd * (nwg >> 3) + pos;
        }
    }
    const int bx = id % nbx, by = id / nbx;
    const int lane = tid & 63, wid = tid >> 6;       // wid 0..7
    const int wr = wid >> 2, wc = wid & 3;           // 2 x 4 wave layout
    const int lr = lane & 15, lg = lane >> 4;
    const int ar = tid >> 3, aq = (tid & 7) << 3;    // 8 consecutive k per thread
    const long arow = (long)(by * 64 + ar) * K;
    const unsigned short* wrh = WTh + (long)(bx * 64 + ar) * Kpad;
    const unsigned short* wrl = WTl + (long)(bx * 64 + ar) * Kpad;
    const bool k4 = (K & 3) == 0;
    const bool k2 = (K & 1) == 0;

    f32x4 acc0 = {0,0,0,0}, acc1 = {0,0,0,0};
    float4 pa0, pa1;                     // raw f32 A staging (cvt deferred to st())
    bf8v pbh, pbl;                       // B bf16 planes

    auto ld = [&](int k0) {              // issue loads ONLY — no use of results
        int kg = k0 + aq;
        if (k4 && kg + 7 < K) {
            pa0 = *(const float4*)&A[arow + kg];
            pa1 = *(const float4*)&A[arow + kg + 4];
        } else if (k2 && kg + 7 < K) {
            float2 f0 = *(const float2*)&A[arow + kg];
            float2 f1 = *(const float2*)&A[arow + kg + 2];
            float2 f2 = *(const float2*)&A[arow + kg + 4];
            float2 f3 = *(const float2*)&A[arow + kg + 6];
            pa0 = make_float4(f0.x, f0.y, f1.x, f1.y);
            pa1 = make_float4(f2.x, f2.y, f3.x, f3.y);
        } else {
            float t[8];
            #pragma unroll
            for (int e = 0; e < 8; e++) t[e] = (kg + e < K) ? A[arow + kg + e] : 0.f;
            pa0 = *(float4*)&t[0];  pa1 = *(float4*)&t[4];
        }
        pbh = *(const bf8v*)(wrh + kg);
        pbl = *(const bf8v*)(wrl + kg);
    };
    auto st = [&](int b) {               // cvt + LDS store — vmcnt wait lands here
        float va[8];
        *(float4*)&va[0] = pa0;  *(float4*)&va[4] = pa1;
        bf8v h0, l0;
        #pragma unroll
        for (int e = 0; e < 8; e++) {
            unsigned short h = f2bf(va[e]);
            h0[e] = (short)h;
            l0[e] = (short)f2bf(va[e] - bfu2f(h));
        }
        *(bf8v*)&Ash[b][ar][aq] = h0;
        *(bf8v*)&Asl[b][ar][aq] = l0;
        *(bf8v*)&Bsh[b][ar][aq] = pbh;
        *(bf8v*)&Bsl[b][ar][aq] = pbl;
    };

    const int nt = (K + 63) >> 6;
    ld(0);
    st(0);
    __syncthreads();
    for (int t = 0; t < nt; t++) {
        const int cur = t & 1;
        const bool more = (t + 1 < nt);
        if (more) ld((t + 1) << 6);      // issue next-tile loads before compute
        #pragma unroll
        for (int ks = 0; ks < 2; ks++) {
            int kb = ks * 32 + lg * 8;
            bf8v a0h = *(const bf8v*)&Ash[cur][wr * 32 + lr][kb];
            bf8v a1h = *(const bf8v*)&Ash[cur][wr * 32 + 16 + lr][kb];
            bf8v a0l = *(const bf8v*)&Asl[cur][wr * 32 + lr][kb];
            bf8v a1l = *(const bf8v*)&Asl[cur][wr * 32 + 16 + lr][kb];
            bf8v b0h = *(const bf8v*)&Bsh[cur][wc * 16 + lr][kb];
            bf8v b0l = *(const bf8v*)&Bsl[cur][wc * 16 + lr][kb];
            acc0 = __builtin_amdgcn_mfma_f32_16x16x32_bf16(a0l, b0h, acc0, 0, 0, 0);
            acc0 = __builtin_amdgcn_mfma_f32_16x16x32_bf16(a0h, b0l, acc0, 0, 0, 0);
            acc0 = __builtin_amdgcn_mfma_f32_16x16x32_bf16(a0h, b0h, acc0, 0, 0, 0);
            acc1 = __builtin_amdgcn_mfma_f32_16x16x32_bf16(a1l, b0h, acc1, 0, 0, 0);
            acc1 = __builtin_amdgcn_mfma_f32_16x16x32_bf16(a1h, b0l, acc1, 0, 0, 0);
            acc1 = __builtin_amdgcn_mfma_f32_16x16x32_bf16(a1h, b0h, acc1, 0, 0, 0);
        }
        if (more) st(cur ^ 1);           // writes other buffer; safe pre-barrier
        __syncthreads();
    }

    // epilogue: C row = rb + lg*4 + g (+16), col = cb + lr  [m89 layout]
    const int isbf = *flag;
    const int rb = by * 64 + wr * 32, cb = bx * 64 + wc * 16;
    {
        int col = cb + lr;
        float bv = bias ? ldw(bias, col, isbf) : 0.f;
        float rv = radd ? radd[col] : 0.f;
        #pragma unroll
        for (int g = 0; g < 4; g++) {
            int row = rb + lg * 4 + g;
            float v = acc0[g] * (rs ? rs[row] : 1.f) + bv
                    + rv * (rsc ? rsc[row] : 1.f);
            if (relu) v = fmaxf(v, 0.f);
            C[(long)row * N + col] = v;
        }
        #pragma unroll
        for (int g = 0; g < 4; g++) {
            int row = rb + 16 + lg * 4 + g;
            float v = acc1[g] * (rs ? rs[row] : 1.f) + bv
                    + rv * (rsc ? rsc[row] : 1.f);
            if (relu) v = fmaxf(v, 0.f);
            C[(long)row * N + col] = v;
        }
    }
}

// ---------------------------------------------------------------- CSR aggregation
// out[d] = relu( dinv[d]*(t[d] + sum_{s in adj(d)} t[s]) + bias ), t prescaled by dinv
// neighbor loop unrolled x4: batch idx loads then 4 independent float4 loads (MLP)
__global__ __launch_bounds__(256) void k_aggr(const float* __restrict__ t,
    const int* __restrict__ offs, const int* __restrict__ bkt,
    const float* __restrict__ dinv, const void* __restrict__ bias,
    float* __restrict__ out, int n, int C, int relu, const int* __restrict__ flag)
{
    const int G = C >> 2;
    long i = blockIdx.x * 256L + threadIdx.x;
    if (i >= (long)n * G) return;
    int d = (int)(i / G), g = (int)(i % G);
    const float4* t4 = (const float4*)t;
    float4 acc = t4[(long)d * G + g];
    int o0 = offs[d], o1 = offs[d + 1];
    int j = o0;
    for (; j + 3 < o1; j += 4) {
        int s0 = bkt[j], s1 = bkt[j + 1], s2 = bkt[j + 2], s3 = bkt[j + 3];
        float4 v0 = t4[(long)s0 * G + g];
        float4 v1 = t4[(long)s1 * G + g];
        float4 v2 = t4[(long)s2 * G + g];
        float4 v3 = t4[(long)s3 * G + g];
        acc.x += v0.x; acc.y += v0.y; acc.z += v0.z; acc.w += v0.w;
        acc.x += v1.x; acc.y += v1.y; acc.z += v1.z; acc.w += v1.w;
        acc.x += v2.x; acc.y += v2.y; acc.z += v2.z; acc.w += v2.w;
        acc.x += v3.x; acc.y += v3.y; acc.z += v3.z; acc.w += v3.w;
    }
    for (; j < o1; j++) {
        int s = bkt[j];
        float4 v = t4[(long)s * G + g];
        acc.x += v.x; acc.y += v.y; acc.z += v.z; acc.w += v.w;
    }
    float dd = dinv[d];
    acc.x *= dd; acc.y *= dd; acc.z *= dd; acc.w *= dd;
    if (bias) {
        int isbf = *flag; int c = g << 2;
        acc.x += ldw(bias, c, isbf); acc.y += ldw(bias, c + 1, isbf);
        acc.z += ldw(bias, c + 2, isbf); acc.w += ldw(bias, c + 3, isbf);
    }
    if (relu) {
        acc.x = fmaxf(acc.x, 0.f); acc.y = fmaxf(acc.y, 0.f);
        acc.z = fmaxf(acc.z, 0.f); acc.w = fmaxf(acc.w, 0.f);
    }
    ((float4*)out)[(long)d * G + g] = acc;
}

// sigma = Ahat @ 1
__global__ void k_sigacc(const int* __restrict__ src, const int* __restrict__ dst,
                         const float* __restrict__ dinv, float* __restrict__ sig, int E) {
    int e = blockIdx.x * 256 + threadIdx.x;
    if (e < E) atomicAdd(&sig[dst[e]], dinv[src[e]]);
}
__global__ void k_sigfin(float* __restrict__ sig, const float* __restrict__ dinv, int n) {
    int i = blockIdx.x * 256 + threadIdx.x;
    if (i < n) sig[i] = dinv[i] * (sig[i] + dinv[i]);
}
__global__ void k_rowvec_acc(const float* __restrict__ gmax, const void* __restrict__ W,
                             float* __restrict__ out, const int* __restrict__ flag) {
    int n = blockIdx.x * 256 + threadIdx.x;
    if (n >= 1024) return;
    const int isbf = *flag;
    int c0 = blockIdx.y * 128;
    float s = 0.f;
    for (int c = c0; c < c0 + 128; c++) s += gmax[c] * ldw(W, (long)c * 1024 + n, isbf);
    atomicAdd(&out[n], s);
}

// ---------------------------------------------------------------- batchnorm + relu (n<=1024)
__global__ __launch_bounds__(256) void k_bn(float* __restrict__ h, const void* __restrict__ gamma,
                                            const void* __restrict__ beta, int n, int C,
                                            const int* __restrict__ flag) {
    int c = blockIdx.x;
    int tid = threadIdx.x;
    __shared__ float sm[256];
    float v[4];
    float s = 0.f;
    #pragma unroll
    for (int u = 0; u < 4; u++) {
        int r = tid + u * 256;
        v[u] = (r < n) ? h[(long)r * C + c] : 0.f;
        s += v[u];
    }
    sm[tid] = s; __syncthreads();
    for (int o = 128; o > 0; o >>= 1) { if (tid < o) sm[tid] += sm[tid + o]; __syncthreads(); }
    float mu = sm[0] / n;
    __syncthreads();
    float s2 = 0.f;
    #pragma unroll
    for (int u = 0; u < 4; u++) {
        int r = tid + u * 256;
        if (r < n) { float d = v[u] - mu; s2 += d * d; }
    }
    sm[tid] = s2; __syncthreads();
    for (int o = 128; o > 0; o >>= 1) { if (tid < o) sm[tid] += sm[tid + o]; __syncthreads(); }
    float var = sm[0] / n;
    float rsq = rsqrtf(var + 1e-5f);
    float g = ldw(gamma, c, *flag), be = ldw(beta, c, *flag);
    #pragma unroll
    for (int u = 0; u < 4; u++) {
        int r = tid + u * 256;
        if (r < n) h[(long)r * C + c] = fmaxf((v[u] - mu) * rsq * g + be, 0.f);
    }
}

// column max of h(1024 x 2048): 32 blocks x 64 cols
__global__ __launch_bounds__(256) void k_cmax(const float* __restrict__ h, float* __restrict__ out) {
    __shared__ float sm[256];
    int coff = threadIdx.x & 63, rq = threadIdx.x >> 6;
    int c = blockIdx.x * 64 + coff;
    float m = -3.0e38f;
    for (int r = rq; r < 1024; r += 4) m = fmaxf(m, h[(long)r * 2048 + c]);
    sm[threadIdx.x] = m;
    __syncthreads();
    if (rq == 0) {
        m = fmaxf(fmaxf(sm[coff], sm[64 + coff]), fmaxf(sm[128 + coff], sm[192 + coff]));
        out[c] = m;
    }
}

// ---------------------------------------------------------------- gather / strided copy
__global__ void k_gather(const float* __restrict__ src, const int* __restrict__ idx,
                         float* __restrict__ dst, int n, int ncol, int ss, int ds, int doff) {
    long i = blockIdx.x * 256L + threadIdx.x;
    if (i < (long)n * ncol) {
        int r = (int)(i / ncol), c = (int)(i % ncol);
        dst[(long)r * ds + doff + c] = src[(long)idx[r] * ss + c];
    }
}
// copy with optional per-row scale (rmul may be nullptr)
__global__ void k_copy(const float* __restrict__ src, float* __restrict__ dst,
                       const float* __restrict__ rmul,
                       int n, int ncol, int ss, int ds, int doff) {
    long i = blockIdx.x * 256L + threadIdx.x;
    if (i < (long)n * ncol) {
        int r = (int)(i / ncol), c = (int)(i % ncol);
        float v = src[(long)r * ss + c];
        if (rmul) v *= rmul[r];
        dst[(long)r * ds + doff + c] = v;
    }
}

// ---------------------------------------------------------------- kNN (k=3), one wave per dst
// psrc packed as float4 (x,y,z,|p|^2); compare on r = ns - 2*dot (== d2 - nd).
// NOTE: top-3 insert is straight-line macro code — a by-reference lambda here
// spilled all state to scratch (VGPR 16->12, WRITE_SIZE 0.5->6.5MB, 2.4x slower).
__device__ __forceinline__ bool knn_better(float d, int i, float D, int I) {
    return d < D || (d == D && i < I);
}
#define KNN_INS(rv, sv)                                                              \
    if ((rv) < bd2) {                                                                \
        if ((rv) < bd0)      { bd2 = bd1; bi2 = bi1; bd1 = bd0; bi1 = bi0;           \
                               bd0 = (rv); bi0 = (sv); }                             \
        else if ((rv) < bd1) { bd2 = bd1; bi2 = bi1; bd1 = (rv); bi1 = (sv); }       \
        else                 { bd2 = (rv); bi2 = (sv); }                             \
    }
__global__ __launch_bounds__(256) void k_knn_w(const float* __restrict__ pdst,
                                               const float4* __restrict__ psrc4,
                                               int M, int Ns,
                                               int* __restrict__ kidx, float* __restrict__ kw) {
    int wid = (blockIdx.x * 256 + threadIdx.x) >> 6;
    int lane = threadIdx.x & 63;
    if (wid >= M) return;
    float x = pdst[wid * 3], y = pdst[wid * 3 + 1], z = pdst[wid * 3 + 2];
    float nd = fmaf(x, x, fmaf(y, y, z * z));
    float bd0 = 3.4e38f, bd1 = 3.4e38f, bd2 = 3.4e38f;
    int bi0 = 0x7fffffff, bi1 = 0x7fffffff, bi2 = 0x7fffffff;
    int s = lane;
    for (; s + 64 < Ns; s += 128) {
        float4 q0 = psrc4[s];
        float4 q1 = psrc4[s + 64];
        float r0 = fmaf(-2.f, fmaf(x, q0.x, fmaf(y, q0.y, z * q0.z)), q0.w);
        float r1 = fmaf(-2.f, fmaf(x, q1.x, fmaf(y, q1.y, z * q1.z)), q1.w);
        KNN_INS(r0, s);
        KNN_INS(r1, s + 64);
    }
    for (; s < Ns; s += 64) {
        float4 q = psrc4[s];
        float r = fmaf(-2.f, fmaf(x, q.x, fmaf(y, q.y, z * q.z)), q.w);
        KNN_INS(r, s);
    }
    #pragma unroll
    for (int off = 32; off >= 1; off >>= 1) {
        float od0 = __shfl_xor(bd0, off, 64); int oi0 = __shfl_xor(bi0, off, 64);
        float od1 = __shfl_xor(bd1, off, 64); int oi1 = __shfl_xor(bi1, off, 64);
        float od2 = __shfl_xor(bd2, off, 64); int oi2 = __shfl_xor(bi2, off, 64);
        float dq[3] = {od0, od1, od2}; int iq[3] = {oi0, oi1, oi2};
        #pragma unroll
        for (int q = 0; q < 3; q++) {
            float dd = dq[q]; int ii = iq[q];
            if (knn_better(dd, ii, bd0, bi0))      { bd2 = bd1; bi2 = bi1; bd1 = bd0; bi1 = bi0; bd0 = dd; bi0 = ii; }
            else if (knn_better(dd, ii, bd1, bi1)) { bd2 = bd1; bi2 = bi1; bd1 = dd; bi1 = ii; }
            else if (knn_better(dd, ii, bd2, bi2)) { bd2 = dd; bi2 = ii; }
        }
    }
    if (lane == 0) {
        kidx[wid * 3] = bi0; kidx[wid * 3 + 1] = bi1; kidx[wid * 3 + 2] = bi2;
        kw[wid * 3]     = 1.0f / fmaxf(nd + bd0, 1e-16f);
        kw[wid * 3 + 1] = 1.0f / fmaxf(nd + bd1, 1e-16f);
        kw[wid * 3 + 2] = 1.0f / fmaxf(nd + bd2, 1e-16f);
    }
}

__global__ void k_knn_apply4(const float* __restrict__ h, const int* __restrict__ kidx,
                             const float* __restrict__ kw, const float* __restrict__ rmul,
                             float* __restrict__ out,
                             int M, int C, int ds) {  // C%4==0, ds%4==0
    const int G = C >> 2;
    long i = blockIdx.x * 256L + threadIdx.x;
    if (i >= (long)M * G) return;
    int r = (int)(i / G), g = (int)(i % G);
    int i0 = kidx[r * 3], i1 = kidx[r * 3 + 1], i2 = kidx[r * 3 + 2];
    float w0 = kw[r * 3], w1 = kw[r * 3 + 1], w2 = kw[r * 3 + 2];
    float inv = 1.0f / (w0 + w1 + w2);
    const float4* h4 = (const float4*)h;
    float4 a = h4[(long)i0 * G + g], b = h4[(long)i1 * G + g], c = h4[(long)i2 * G + g];
    float4 o;
    o.x = (w0 * a.x + w1 * b.x + w2 * c.x) * inv;
    o.y = (w0 * a.y + w1 * b.y + w2 * c.y) * inv;
    o.z = (w0 * a.z + w1 * b.z + w2 * c.z) * inv;
    o.w = (w0 * a.w + w1 * b.w + w2 * c.w) * inv;
    if (rmul) {
        float dd = rmul[r];
        o.x *= dd; o.y *= dd; o.z *= dd; o.w *= dd;
    }
    *(float4*)&out[(long)r * ds + (g << 2)] = o;
}
__global__ void k_knn_apply2(const float* __restrict__ h, const int* __restrict__ kidx,
                             const float* __restrict__ kw, float* __restrict__ out,
                             int M, int C, int ds) {  // C%2==0, ds%2==0
    const int G = C >> 1;
    long i = blockIdx.x * 256L + threadIdx.x;
    if (i >= (long)M * G) return;
    int r = (int)(i / G), g = (int)(i % G);
    int i0 = kidx[r * 3], i1 = kidx[r * 3 + 1], i2 = kidx[r * 3 + 2];
    float w0 = kw[r * 3], w1 = kw[r * 3 + 1], w2 = kw[r * 3 + 2];
    float inv = 1.0f / (w0 + w1 + w2);
    const float2* h2 = (const float2*)h;
    float2 a = h2[(long)i0 * G + g], b = h2[(long)i1 * G + g], c = h2[(long)i2 * G + g];
    float2 o;
    o.x = (w0 * a.x + w1 * b.x + w2 * c.x) * inv;
    o.y = (w0 * a.y + w1 * b.y + w2 * c.y) * inv;
    *(float2*)&out[(long)r * ds + (g << 1)] = o;
}

// ---------------------------------------------------------------- launch
extern "C" void kernel_launch(void* const* d_in, const int* in_sizes, int n_in,
                              void* d_out, int out_size, void* d_ws, size_t ws_size,
                              hipStream_t stream) {
    const int N0 = 16384, N1 = 4096, N2 = 1024;
    const int E0 = in_sizes[48] / 2, E1 = in_sizes[49] / 2, E2 = in_sizes[50] / 2;

    const int* idx0 = (const int*)d_in[46];
    const int* idx1 = (const int*)d_in[47];
    const int* ei0  = (const int*)d_in[48];
    const int* ei1  = (const int*)d_in[49];
    const int* ei2  = (const int*)d_in[50];

    float* W = (float*)d_ws;
    size_t off = 0;
    auto alloc = [&](size_t nf) { float* p = W + off; off += (nf + 63) & ~(size_t)63; return p; };
    auto allocU = [&](size_t nu) { return (unsigned short*)alloc((nu + 1) / 2); };
    float* P     = alloc(4194304);   // 16384x256 == 4096x1024 == 1024x2048(+)
    float* Q     = alloc(4194304);
    float* CAT   = alloc(8486912);   // 16384x518 >= 16384x256 >= 4096x320
    float* xf    = alloc(98304);     // 16384x6 (also final 16384x4 out)
    float* posf  = alloc(49152);
    float* pos1  = alloc(12288);
    float* pos2  = alloc(3072);
    float* pos1p = alloc(16384);     // 4096 float4 packed
    float* pos2p = alloc(4096);      // 1024 float4 packed
    float* dinv0 = alloc(16384);
    float* dinv1 = alloc(4096);
    float* dinv2 = alloc(1024);
    float* x1    = alloc(262144);    // 4096x64
    float* c2    = alloc(134144);    // 1024x131
    float* xb    = alloc(262144);    // 1024x256
    float* gmaxb = alloc(2048);
    float* rowv  = alloc(1024);
    float* sigb  = alloc(4096);
    float* kwb   = alloc(49152);
    int*   kib   = (int*)alloc(49152);
    int*   flg   = (int*)alloc(64);
    int*   cntb  = (int*)alloc(16384);
    int*   offs0 = (int*)alloc(16448);
    int*   offs1 = (int*)alloc(4160);
    int*   offs2 = (int*)alloc(1088);
    int*   bkt0  = (int*)alloc(E0);
    int*   bkt1  = (int*)alloc(E1);
    int*   bkt2  = (int*)alloc(E2);

    // bf16 W^T hi/lo planes (N x Kpad each) — appended last; guard below disables
    // the MFMA path entirely if they don't fit in ws.
    struct WtPair { unsigned short *h, *l; int Kp; };
    auto mkwt = [&](size_t n, int Kp) {
        WtPair p; p.h = allocU(n); p.l = allocU(n); p.Kp = Kp; return p;
    };
    WtPair wt6  = mkwt(64 * 64, 64);
    WtPair wt8  = mkwt(64 * 128, 128);
    WtPair wt10 = mkwt(64 * 64, 64);
    WtPair wt12 = mkwt(128 * 64, 64);
    WtPair wt14 = mkwt(128 * 192, 192);
    WtPair wt16 = mkwt(128 * 128, 128);
    WtPair wt18 = mkwt(256 * 128, 128);
    WtPair wt20 = mkwt(512 * 192, 192);
    WtPair wt22 = mkwt(1024 * 512, 512);
    WtPair wt24 = mkwt(2048 * 1024, 1024);
    WtPair wt30 = mkwt(1024 * 320, 320);
    WtPair wt32 = mkwt(1024 * 1024, 1024);
    WtPair wt34 = mkwt(512 * 1024, 1024);
    WtPair wt36 = mkwt(256 * 576, 576);
    WtPair wt38 = mkwt(256 * 256, 256);
    WtPair wt40 = mkwt(128 * 256, 256);
    WtPair wt42 = mkwt(64 * 128, 128);

    const bool usex = (off * sizeof(float)) <= ws_size;

    auto g1 = [](long n) { return dim3((unsigned)((n + 255) / 256)); };

    auto mm = [&](const float* Ain, int iw, int ib, const float* radd, const float* rsc,
                  const float* rs, float* out, int M_, int K_, int N_, long woff, int relu) {
        dim3 g((N_ + 63) / 64, M_ / 64);
        k_mm<<<g, 256, 0, stream>>>(Ain, d_in[iw], ib >= 0 ? d_in[ib] : nullptr,
                                    radd, rsc, rs, out, M_, K_, N_, woff, relu, flg);
    };
    auto mmx = [&](const float* Ain, int iw, int ib, const float* radd, const float* rsc,
                   const float* rs, float* out, int M_, int K_, int N_, long woff, int relu,
                   const WtPair& wp) {
        if (usex) {
            dim3 g(N_ / 64, M_ / 64);
            k_mmx<<<g, 512, 0, stream>>>(Ain, wp.h, wp.l,
                                         ib >= 0 ? d_in[ib] : nullptr,
                                         radd, rsc, rs, out, M_, K_, wp.Kp, N_, relu, flg);
        } else {
            mm(Ain, iw, ib, radd, rsc, rs, out, M_, K_, N_, woff, relu);
        }
    };
    auto gcnx = [&](const float* Ain, int n, int K, int iw, int ib, int C,
                    const int* offs, const int* bkt, const float* dinv, float* t, float* out,
                    const WtPair& wp) {
        mmx(Ain, iw, -1, nullptr, nullptr, dinv, t, n, K, C, 0, 0, wp);
        k_aggr<<<g1((long)n * (C >> 2)), 256, 0, stream>>>(t, offs, bkt, dinv, d_in[ib],
                                                           out, n, C, 1, flg);
    };
    auto gcn = [&](const float* Ain, int n, int K, int iw, int ib, int C,
                   const int* offs, const int* bkt, const float* dinv, float* t, float* out) {
        mm(Ain, iw, -1, nullptr, nullptr, dinv, t, n, K, C, 0, 0);
        k_aggr<<<g1((long)n * (C >> 2)), 256, 0, stream>>>(t, offs, bkt, dinv, d_in[ib],
                                                           out, n, C, 1, flg);
    };
    auto csr = [&](const int* ei, int E, int n, int* offs, int* bkt, float* dinv) {
        k_zero_i<<<g1(n), 256, 0, stream>>>(cntb, n);
        k_count<<<g1(E), 256, 0, stream>>>(ei + E, cntb, E);
        k_dinv_i<<<g1(n), 256, 0, stream>>>(cntb, dinv, n);
        k_scan<<<1, 1024, 0, stream>>>(cntb, offs, n);
        k_zero_i<<<g1(n), 256, 0, stream>>>(cntb, n);
        k_fill<<<g1(E), 256, 0, stream>>>(ei, ei + E, offs, cntb, bkt, E);
    };
    auto wtk = [&](int iw, long woff, int K_, int N_, const WtPair& wp) {
        if (!usex) return;
        dim3 g(N_ / 32, wp.Kp / 32);
        k_wt<<<g, 256, 0, stream>>>(d_in[iw], woff, wp.h, wp.l, K_, N_, wp.Kp, flg);
    };

    // dtype detection + input conversion + CSR + weight transposes
    k_detect<<<1, 256, 0, stream>>>((const unsigned short*)d_in[2], in_sizes[2], flg);
    k_cvt_in<<<g1(N0 * 6), 256, 0, stream>>>(d_in[0], xf, N0 * 6, flg);
    k_cvt_in<<<g1(N0 * 3), 256, 0, stream>>>(d_in[1], posf, N0 * 3, flg);
    csr(ei0, E0, N0, offs0, bkt0, dinv0);
    csr(ei1, E1, N1, offs1, bkt1, dinv1);
    csr(ei2, E2, N2, offs2, bkt2, dinv2);
    wtk(6, 0, 32, 64, wt6);
    wtk(8, 0, 67, 64, wt8);
    wtk(10, 0, 64, 64, wt10);
    wtk(12, 0, 64, 128, wt12);
    wtk(14, 0, 131, 128, wt14);
    wtk(16, 0, 128, 128, wt16);
    wtk(18, 0, 128, 256, wt18);
    wtk(20, 0, 131, 512, wt20);
    wtk(22, 0, 512, 1024, wt22);
    wtk(24, 0, 1024, 2048, wt24);
    wtk(30, 2048L * 1024L, 320, 1024, wt30);
    wtk(32, 0, 1024, 1024, wt32);
    wtk(34, 0, 1024, 512, wt34);
    wtk(36, 0, 518, 256, wt36);
    wtk(38, 0, 256, 256, wt38);
    wtk(40, 0, 256, 128, wt40);
    wtk(42, 0, 128, 64, wt42);

    // SA1: 6->32->32->64 on level-0 graph  (N=32 layers stay fp32)
    gcn(xf, N0, 6, 2, 3, 32, offs0, bkt0, dinv0, P, Q);
    gcn(Q, N0, 32, 4, 5, 32, offs0, bkt0, dinv0, P, Q);
    gcnx(Q, N0, 32, 6, 7, 64, offs0, bkt0, dinv0, P, Q, wt6);
    k_gather<<<g1((long)N1 * 64), 256, 0, stream>>>(Q, idx0, x1, N1, 64, 64, 64, 0);
    k_gather<<<g1((long)N1 * 3), 256, 0, stream>>>(posf, idx0, pos1, N1, 3, 3, 3, 0);

    // SA2: [x1|pos1](67) -> 64->64->128 on level-1 graph
    k_copy<<<g1((long)N1 * 64), 256, 0, stream>>>(x1, P, nullptr, N1, 64, 64, 67, 0);
    k_copy<<<g1((long)N1 * 3), 256, 0, stream>>>(pos1, P, nullptr, N1, 3, 3, 67, 64);
    gcnx(P, N1, 67, 8, 9, 64, offs1, bkt1, dinv1, Q, P, wt8);
    gcnx(P, N1, 64, 10, 11, 64, offs1, bkt1, dinv1, Q, P, wt10);
    gcnx(P, N1, 64, 12, 13, 128, offs1, bkt1, dinv1, Q, P, wt12);
    k_gather<<<g1((long)N2 * 128), 256, 0, stream>>>(P, idx1, c2, N2, 128, 128, 131, 0);
    k_gather<<<g1((long)N2 * 3), 256, 0, stream>>>(pos1, idx1, pos2, N2, 3, 3, 3, 0);
    k_copy<<<g1((long)N2 * 3), 256, 0, stream>>>(pos2, c2, nullptr, N2, 3, 3, 131, 128);

    // bottleneck: 131 -> 128->128->256 on level-2 graph
    gcnx(c2, N2, 131, 14, 15, 128, offs2, bkt2, dinv2, P, Q, wt14);
    gcnx(Q, N2, 128, 16, 17, 128, offs2, bkt2, dinv2, P, Q, wt16);
    gcnx(Q, N2, 128, 18, 19, 256, offs2, bkt2, dinv2, P, xb, wt18);

    // GlobalSA
    mmx(c2, 20, 21, nullptr, nullptr, nullptr, P, N2, 131, 512, 0, 0, wt20);
    k_bn<<<dim3(512), 256, 0, stream>>>(P, d_in[26], d_in[27], N2, 512, flg);
    mmx(P, 22, 23, nullptr, nullptr, nullptr, Q, N2, 512, 1024, 0, 0, wt22);
    k_bn<<<dim3(1024), 256, 0, stream>>>(Q, d_in[28], d_in[29], N2, 1024, flg);
    mmx(Q, 24, 25, nullptr, nullptr, nullptr, P, N2, 1024, 2048, 0, 0, wt24);
    k_cmax<<<dim3(32), 256, 0, stream>>>(P, gmaxb);

    // FP2: out1 = relu( (Ahat [interp(xb)|x1]) @ W[2048:] + sigma*rowv + b )
    k_zero<<<g1(1024), 256, 0, stream>>>(rowv, 1024);
    k_rowvec_acc<<<dim3(4, 16), 256, 0, stream>>>(gmaxb, d_in[30], rowv, flg);
    k_pack4<<<g1(N1), 256, 0, stream>>>(pos1, (float4*)pos1p, N1);
    k_pack4<<<g1(N2), 256, 0, stream>>>(pos2, (float4*)pos2p, N2);
    k_knn_w<<<g1((long)N1 * 64), 256, 0, stream>>>(pos1, (const float4*)pos2p, N1, N2, kib, kwb);
    k_knn_apply4<<<g1((long)N1 * 64), 256, 0, stream>>>(xb, kib, kwb, dinv1, CAT, N1, 256, 320);
    k_copy<<<g1((long)N1 * 64), 256, 0, stream>>>(x1, CAT, dinv1, N1, 64, 64, 320, 256);
    k_aggr<<<g1((long)N1 * 80), 256, 0, stream>>>(CAT, offs1, bkt1, dinv1, nullptr,
                                                  P, N1, 320, 0, flg);
    k_zero<<<g1(N1), 256, 0, stream>>>(sigb, N1);
    k_sigacc<<<g1(E1), 256, 0, stream>>>(ei1, ei1 + E1, dinv1, sigb, E1);
    k_sigfin<<<g1(N1), 256, 0, stream>>>(sigb, dinv1, N1);
    mmx(P, 30, 31, rowv, sigb, nullptr, Q, N1, 320, 1024, 2048L * 1024L, 1, wt30);
    gcnx(Q, N1, 1024, 32, 33, 1024, offs1, bkt1, dinv1, P, Q, wt32);
    gcnx(Q, N1, 1024, 34, 35, 512, offs1, bkt1, dinv1, P, Q, wt34);  // Q: 4096x512

    // FP1
    k_knn_w<<<g1((long)N0 * 64), 256, 0, stream>>>(posf, (const float4*)pos1p, N0, N1, kib, kwb);
    k_knn_apply2<<<g1((long)N0 * 256), 256, 0, stream>>>(Q, kib, kwb, CAT, N0, 512, 518);
    k_copy<<<g1((long)N0 * 6), 256, 0, stream>>>(xf, CAT, nullptr, N0, 6, 6, 518, 512);
    gcnx(CAT, N0, 518, 36, 37, 256, offs0, bkt0, dinv0, P, Q, wt36);
    gcnx(Q, N0, 256, 38, 39, 256, offs0, bkt0, dinv0, P, CAT, wt38);
    gcnx(CAT, N0, 256, 40, 41, 128, offs0, bkt0, dinv0, P, Q, wt40);

    // final MLP: 128 -> 64 (relu) -> 4
    mmx(Q, 42, 43, nullptr, nullptr, nullptr, P, N0, 128, 64, 0, 1, wt42);
    mm(P, 44, 45, nullptr, nullptr, nullptr, xf, N0, 64, 4, 0, 0);
    k_out<<<g1(N0 * 4), 256, 0, stream>>>(xf, d_out, N0 * 4, flg);
}

// Round 16
// 1020.977 us; speedup vs baseline: 1.0406x; 1.0211x over previous
//
#include <hip/hip_runtime.h>
#include <hip/hip_bf16.h>

typedef __hip_bfloat16 bf16;
typedef __attribute__((ext_vector_type(8))) short bf8v;   // 8 bf16 (4 VGPR)
typedef __attribute__((ext_vector_type(4))) float f32x4;  // MFMA acc

// flag: 1 = float tensors are bf16, 0 = fp32
__device__ __forceinline__ float ldw(const void* p, long i, int isbf) {
    return isbf ? __bfloat162float(((const bf16*)p)[i]) : ((const float*)p)[i];
}
__device__ __forceinline__ unsigned short f2bf(float v) {
    bf16 h = __float2bfloat16(v);
    return *reinterpret_cast<unsigned short*>(&h);
}
__device__ __forceinline__ float bfu2f(unsigned short u) {
    return __uint_as_float((unsigned)u << 16);
}

// ---------------------------------------------------------------- dtype detect
__global__ void k_detect(const unsigned short* __restrict__ w, int n, int* __restrict__ flag) {
    __shared__ int cnt;
    if (threadIdx.x == 0) cnt = 0;
    __syncthreads();
    int bad = 0;
    for (int i = threadIdx.x; i < n; i += 256) {
        int e = (w[i] >> 7) & 0xFF;
        if (e == 0xFF || (e != 0 && (e < 64 || e > 190))) bad++;
    }
    atomicAdd(&cnt, bad);
    __syncthreads();
    if (threadIdx.x == 0) *flag = (cnt > n / 16) ? 0 : 1;
}

// ---------------------------------------------------------------- small utils
__global__ void k_cvt_in(const void* __restrict__ s, float* __restrict__ d, int n,
                         const int* __restrict__ flag) {
    int i = blockIdx.x * 256 + threadIdx.x;
    if (i < n) d[i] = ldw(s, i, *flag);
}
__global__ void k_out(const float* __restrict__ s, void* __restrict__ d, int n,
                      const int* __restrict__ flag) {
    int i = blockIdx.x * 256 + threadIdx.x;
    if (i < n) {
        if (*flag) ((bf16*)d)[i] = __float2bfloat16(s[i]);
        else       ((float*)d)[i] = s[i];
    }
}
__global__ void k_zero(float* __restrict__ d, int n) {
    int i = blockIdx.x * 256 + threadIdx.x;
    if (i < n) d[i] = 0.f;
}
__global__ void k_zero_i(int* __restrict__ d, int n) {
    int i = blockIdx.x * 256 + threadIdx.x;
    if (i < n) d[i] = 0;
}
// pack (x,y,z) triplets -> float4 (x,y,z,|p|^2)
__global__ void k_pack4(const float* __restrict__ p, float4* __restrict__ o, int n) {
    int i = blockIdx.x * 256 + threadIdx.x;
    if (i < n) {
        float x = p[3 * i], y = p[3 * i + 1], z = p[3 * i + 2];
        float4 v = {x, y, z, fmaf(x, x, fmaf(y, y, z * z))};
        o[i] = v;
    }
}

// ---------------------------------------------------------------- CSR build
__global__ void k_count(const int* __restrict__ dst, int* __restrict__ cnt, int E) {
    int i = blockIdx.x * 256 + threadIdx.x;
    if (i < E) atomicAdd(&cnt[dst[i]], 1);
}
__global__ void k_dinv_i(const int* __restrict__ cnt, float* __restrict__ dinv, int n) {
    int i = blockIdx.x * 256 + threadIdx.x;
    if (i < n) dinv[i] = rsqrtf((float)cnt[i] + 1.0f);  // +1 self loop
}
// single block, 1024 threads, exclusive scan of cnt[0..n) -> offs, offs[n]=E
__global__ __launch_bounds__(1024) void k_scan(const int* __restrict__ cnt,
                                               int* __restrict__ offs, int n) {
    __shared__ int sm[1024];
    int t = threadIdx.x;
    int chunk = (n + 1023) >> 10;
    int b0 = t * chunk, b1 = min(b0 + chunk, n);
    int s = 0;
    for (int i = b0; i < b1; i++) s += cnt[i];
    sm[t] = s;
    __syncthreads();
    for (int o = 1; o < 1024; o <<= 1) {
        int v = (t >= o) ? sm[t - o] : 0;
        __syncthreads();
        sm[t] += v;
        __syncthreads();
    }
    int run = sm[t] - s;  // exclusive
    for (int i = b0; i < b1; i++) { offs[i] = run; run += cnt[i]; }
    if (t == 1023) offs[n] = sm[1023];
}
__global__ void k_fill(const int* __restrict__ src, const int* __restrict__ dst,
                       const int* __restrict__ offs, int* __restrict__ cur,
                       int* __restrict__ bkt, int E) {
    int e = blockIdx.x * 256 + threadIdx.x;
    if (e < E) {
        int d = dst[e];
        int p = atomicAdd(&cur[d], 1);
        bkt[offs[d] + p] = src[e];
    }
}

// ---------------------------------------------------------------- weight transpose + hi/lo split
// W (KxN, flagged dtype, offset woff) -> WTh/WTl (N x Kpad bf16), zero-pad k>=K
// grid (N/32, Kpad/32), 256 threads
__global__ __launch_bounds__(256) void k_wt(const void* __restrict__ W, long woff,
                                            unsigned short* __restrict__ WTh,
                                            unsigned short* __restrict__ WTl,
                                            int K, int N, int Kpad,
                                            const int* __restrict__ flag) {
    __shared__ unsigned short th[32][33];
    __shared__ unsigned short tl[32][33];
    const int isbf = *flag;
    int n0 = blockIdx.x * 32, k0 = blockIdx.y * 32;
    int c = threadIdx.x & 31, r = threadIdx.x >> 5;   // r 0..7
    #pragma unroll
    for (int u = 0; u < 4; u++) {
        int k = k0 + r + u * 8;
        float v = (k < K) ? ldw(W, woff + (long)k * N + n0 + c, isbf) : 0.f;
        unsigned short h = f2bf(v);
        th[r + u * 8][c] = h;
        tl[r + u * 8][c] = f2bf(v - bfu2f(h));
    }
    __syncthreads();
    #pragma unroll
    for (int u = 0; u < 4; u++) {
        int n = n0 + r + u * 8;
        WTh[(long)n * Kpad + k0 + c] = th[c][r + u * 8];
        WTl[(long)n * Kpad + k0 + c] = tl[c][r + u * 8];
    }
}

// ---------------------------------------------------------------- matmul (fp32, generic)
__global__ __launch_bounds__(256) void k_mm(
    const float* __restrict__ A, const void* __restrict__ Wt,
    const void* __restrict__ bias, const float* __restrict__ radd,
    const float* __restrict__ rsc, const float* __restrict__ rs,
    float* __restrict__ C, int M, int K, int N, long woff, int relu,
    const int* __restrict__ flag)
{
    __shared__ float As[2][16][68];
    __shared__ float Bs[2][16][68];
    const int isbf = *flag;
    const int tid = threadIdx.x;
    const int tx = tid & 15, ty = tid >> 4;
    const int bx = blockIdx.x, by = blockIdx.y;

    const int ar = tid >> 2, aq = (tid & 3) << 2;
    const long arow = (long)(by * 64 + ar) * K;
    const int bkk = tid >> 4, bn4 = (tid & 15) << 2;
    const int bcol0 = bx * 64 + bn4;

    float acc[4][4] = {};
    float4 pa, pb;

    auto loadAB = [&](int k0) {
        int kg = k0 + aq;
        pa.x = (kg + 0 < K) ? A[arow + kg + 0] : 0.f;
        pa.y = (kg + 1 < K) ? A[arow + kg + 1] : 0.f;
        pa.z = (kg + 2 < K) ? A[arow + kg + 2] : 0.f;
        pa.w = (kg + 3 < K) ? A[arow + kg + 3] : 0.f;
        int kb = k0 + bkk;
        pb = make_float4(0.f, 0.f, 0.f, 0.f);
        if (kb < K) {
            long base = woff + (long)kb * N + bcol0;
            if (bcol0 + 3 < N) {
                pb.x = ldw(Wt, base + 0, isbf); pb.y = ldw(Wt, base + 1, isbf);
                pb.z = ldw(Wt, base + 2, isbf); pb.w = ldw(Wt, base + 3, isbf);
            } else {
                if (bcol0 < N)     pb.x = ldw(Wt, base + 0, isbf);
                if (bcol0 + 1 < N) pb.y = ldw(Wt, base + 1, isbf);
                if (bcol0 + 2 < N) pb.z = ldw(Wt, base + 2, isbf);
            }
        }
    };
    auto storeAB = [&](int b) {
        As[b][aq + 0][ar] = pa.x;  As[b][aq + 1][ar] = pa.y;
        As[b][aq + 2][ar] = pa.z;  As[b][aq + 3][ar] = pa.w;
        *(float4*)&Bs[b][bkk][bn4] = pb;
    };

    loadAB(0);
    storeAB(0);
    __syncthreads();

    const int nk = (K + 15) >> 4;
    for (int t = 0; t < nk; t++) {
        const int cur = t & 1;
        const bool more = (t + 1 < nk);
        if (more) loadAB((t + 1) << 4);
        #pragma unroll
        for (int kk = 0; kk < 16; kk++) {
            float4 a = *(const float4*)&As[cur][kk][ty << 2];
            float4 b = *(const float4*)&Bs[cur][kk][tx << 2];
            float av[4] = {a.x, a.y, a.z, a.w};
            float bv[4] = {b.x, b.y, b.z, b.w};
            #pragma unroll
            for (int i = 0; i < 4; i++)
                #pragma unroll
                for (int j = 0; j < 4; j++)
                    acc[i][j] = fmaf(av[i], bv[j], acc[i][j]);
        }
        if (more) storeAB(cur ^ 1);
        __syncthreads();
    }

    const int col = bx * 64 + (tx << 2);
    #pragma unroll
    for (int i = 0; i < 4; i++) {
        int r = by * 64 + (ty << 2) + i;
        float m = rs ? rs[r] : 1.0f;
        float rr = rsc ? rsc[r] : 1.0f;
        float v[4];
        #pragma unroll
        for (int j = 0; j < 4; j++) {
            v[j] = acc[i][j] * m;
            int c = col + j;
            if (c < N) {
                if (bias) v[j] += ldw(bias, c, isbf);
                if (radd) v[j] += radd[c] * rr;
            }
            if (relu) v[j] = fmaxf(v[j], 0.f);
        }
        if (col + 3 < N) {
            float4 o = {v[0], v[1], v[2], v[3]};
            *(float4*)&C[(long)r * N + col] = o;
        } else {
            for (int j = 0; j < 4; j++)
                if (col + j < N) C[(long)r * N + col + j] = v[j];
        }
    }
}

// ---------------------------------------------------------------- matmul (MFMA bf16x3)
// fp32 accuracy via hi/lo bf16 split: a*b ~= al*bh + ah*bl + ah*bh (fp32 accum).
// FINAL (== round 13, measured best 1025.7us end-to-end, hot dispatch 50.3us):
// 512 threads / 8 waves (2x4 layout, wave=32x16, acc=2 f32x4), 64x64 tile,
// single LDS buffer 36.9KB -> 4 blocks/CU (61% occ), 1-deep ld/st split
// (raw loads in ld(), cvt at st() so the vmcnt wait is covered by compute),
// float2 A-tier for K%2==0 (K=518 hot shape), XCD-aware swizzle.
// Closed arms: 2-deep prefetch (r9 spill; r14 L2 thrash FETCH 25->40MB),
// LDS dbuf (r15: 2 blocks/CU lost L2 co-residency, FETCH 25->41MB),
// occupancy x2 (r13: null - lockstep blocks stall together).
__global__ __launch_bounds__(512, 8) void k_mmx(
    const float* __restrict__ A,
    const unsigned short* __restrict__ WTh, const unsigned short* __restrict__ WTl,
    const void* __restrict__ bias, const float* __restrict__ radd,
    const float* __restrict__ rsc, const float* __restrict__ rs,
    float* __restrict__ C, int M, int K, int Kpad, int N, int relu,
    const int* __restrict__ flag)
{
    __shared__ unsigned short Ash[64][72];
    __shared__ unsigned short Asl[64][72];
    __shared__ unsigned short Bsh[64][72];
    __shared__ unsigned short Bsl[64][72];
    const int tid = threadIdx.x;
    // XCD-aware swizzle (FETCH 75->19MB measured); bijective iff nwg%8==0.
    const int nbx = gridDim.x;
    int id = blockIdx.y * nbx + blockIdx.x;
    {
        int nwg = nbx * gridDim.y;
        if ((nwg & 7) == 0) {
            int xcd = id & 7, pos = id >> 3;
            id = xcd * (nwg >> 3) + pos;
        }
    }
    const int bx = id % nbx, by = id / nbx;
    const int lane = tid & 63, wid = tid >> 6;       // wid 0..7
    const int wr = wid >> 2, wc = wid & 3;           // 2 x 4 wave layout
    const int lr = lane & 15, lg = lane >> 4;
    const int ar = tid >> 3, aq = (tid & 7) << 3;    // 8 consecutive k per thread
    const long arow = (long)(by * 64 + ar) * K;
    const unsigned short* wrh = WTh + (long)(bx * 64 + ar) * Kpad;
    const unsigned short* wrl = WTl + (long)(bx * 64 + ar) * Kpad;
    const bool k4 = (K & 3) == 0;
    const bool k2 = (K & 1) == 0;

    f32x4 acc0 = {0,0,0,0}, acc1 = {0,0,0,0};
    float4 pa0, pa1;                     // raw f32 A staging (cvt deferred to st())
    bf8v pbh, pbl;                       // B bf16 planes

    auto ld = [&](int k0) {              // issue loads ONLY — no use of results
        int kg = k0 + aq;
        if (k4 && kg + 7 < K) {
            pa0 = *(const float4*)&A[arow + kg];
            pa1 = *(const float4*)&A[arow + kg + 4];
        } else if (k2 && kg + 7 < K) {
            float2 f0 = *(const float2*)&A[arow + kg];
            float2 f1 = *(const float2*)&A[arow + kg + 2];
            float2 f2 = *(const float2*)&A[arow + kg + 4];
            float2 f3 = *(const float2*)&A[arow + kg + 6];
            pa0 = make_float4(f0.x, f0.y, f1.x, f1.y);
            pa1 = make_float4(f2.x, f2.y, f3.x, f3.y);
        } else {
            float t[8];
            #pragma unroll
            for (int e = 0; e < 8; e++) t[e] = (kg + e < K) ? A[arow + kg + e] : 0.f;
            pa0 = *(float4*)&t[0];  pa1 = *(float4*)&t[4];
        }
        pbh = *(const bf8v*)(wrh + kg);
        pbl = *(const bf8v*)(wrl + kg);
    };
    auto st = [&]() {                    // cvt + LDS store — vmcnt wait lands here
        float va[8];
        *(float4*)&va[0] = pa0;  *(float4*)&va[4] = pa1;
        bf8v h0, l0;
        #pragma unroll
        for (int e = 0; e < 8; e++) {
            unsigned short h = f2bf(va[e]);
            h0[e] = (short)h;
            l0[e] = (short)f2bf(va[e] - bfu2f(h));
        }
        *(bf8v*)&Ash[ar][aq] = h0;
        *(bf8v*)&Asl[ar][aq] = l0;
        *(bf8v*)&Bsh[ar][aq] = pbh;
        *(bf8v*)&Bsl[ar][aq] = pbl;
    };

    ld(0);
    for (int k0 = 0; k0 < K; k0 += 64) {
        __syncthreads();    // previous tile's fragment reads complete
        st();
        __syncthreads();
        if (k0 + 64 < K) ld(k0 + 64);    // issue next-tile loads; consumed next iter
        #pragma unroll
        for (int ks = 0; ks < 2; ks++) {
            int kb = ks * 32 + lg * 8;
            bf8v a0h = *(const bf8v*)&Ash[wr * 32 + lr][kb];
            bf8v a1h = *(const bf8v*)&Ash[wr * 32 + 16 + lr][kb];
            bf8v a0l = *(const bf8v*)&Asl[wr * 32 + lr][kb];
            bf8v a1l = *(const bf8v*)&Asl[wr * 32 + 16 + lr][kb];
            bf8v b0h = *(const bf8v*)&Bsh[wc * 16 + lr][kb];
            bf8v b0l = *(const bf8v*)&Bsl[wc * 16 + lr][kb];
            acc0 = __builtin_amdgcn_mfma_f32_16x16x32_bf16(a0l, b0h, acc0, 0, 0, 0);
            acc0 = __builtin_amdgcn_mfma_f32_16x16x32_bf16(a0h, b0l, acc0, 0, 0, 0);
            acc0 = __builtin_amdgcn_mfma_f32_16x16x32_bf16(a0h, b0h, acc0, 0, 0, 0);
            acc1 = __builtin_amdgcn_mfma_f32_16x16x32_bf16(a1l, b0h, acc1, 0, 0, 0);
            acc1 = __builtin_amdgcn_mfma_f32_16x16x32_bf16(a1h, b0l, acc1, 0, 0, 0);
            acc1 = __builtin_amdgcn_mfma_f32_16x16x32_bf16(a1h, b0h, acc1, 0, 0, 0);
        }
    }

    // epilogue: C row = rb + lg*4 + g (+16), col = cb + lr  [m89 layout]
    const int isbf = *flag;
    const int rb = by * 64 + wr * 32, cb = bx * 64 + wc * 16;
    {
        int col = cb + lr;
        float bv = bias ? ldw(bias, col, isbf) : 0.f;
        float rv = radd ? radd[col] : 0.f;
        #pragma unroll
        for (int g = 0; g < 4; g++) {
            int row = rb + lg * 4 + g;
            float v = acc0[g] * (rs ? rs[row] : 1.f) + bv
                    + rv * (rsc ? rsc[row] : 1.f);
            if (relu) v = fmaxf(v, 0.f);
            C[(long)row * N + col] = v;
        }
        #pragma unroll
        for (int g = 0; g < 4; g++) {
            int row = rb + 16 + lg * 4 + g;
            float v = acc1[g] * (rs ? rs[row] : 1.f) + bv
                    + rv * (rsc ? rsc[row] : 1.f);
            if (relu) v = fmaxf(v, 0.f);
            C[(long)row * N + col] = v;
        }
    }
}

// ---------------------------------------------------------------- CSR aggregation
// out[d] = relu( dinv[d]*(t[d] + sum_{s in adj(d)} t[s]) + bias ), t prescaled by dinv
// neighbor loop unrolled x4: batch idx loads then 4 independent float4 loads (MLP)
__global__ __launch_bounds__(256) void k_aggr(const float* __restrict__ t,
    const int* __restrict__ offs, const int* __restrict__ bkt,
    const float* __restrict__ dinv, const void* __restrict__ bias,
    float* __restrict__ out, int n, int C, int relu, const int* __restrict__ flag)
{
    const int G = C >> 2;
    long i = blockIdx.x * 256L + threadIdx.x;
    if (i >= (long)n * G) return;
    int d = (int)(i / G), g = (int)(i % G);
    const float4* t4 = (const float4*)t;
    float4 acc = t4[(long)d * G + g];
    int o0 = offs[d], o1 = offs[d + 1];
    int j = o0;
    for (; j + 3 < o1; j += 4) {
        int s0 = bkt[j], s1 = bkt[j + 1], s2 = bkt[j + 2], s3 = bkt[j + 3];
        float4 v0 = t4[(long)s0 * G + g];
        float4 v1 = t4[(long)s1 * G + g];
        float4 v2 = t4[(long)s2 * G + g];
        float4 v3 = t4[(long)s3 * G + g];
        acc.x += v0.x; acc.y += v0.y; acc.z += v0.z; acc.w += v0.w;
        acc.x += v1.x; acc.y += v1.y; acc.z += v1.z; acc.w += v1.w;
        acc.x += v2.x; acc.y += v2.y; acc.z += v2.z; acc.w += v2.w;
        acc.x += v3.x; acc.y += v3.y; acc.z += v3.z; acc.w += v3.w;
    }
    for (; j < o1; j++) {
        int s = bkt[j];
        float4 v = t4[(long)s * G + g];
        acc.x += v.x; acc.y += v.y; acc.z += v.z; acc.w += v.w;
    }
    float dd = dinv[d];
    acc.x *= dd; acc.y *= dd; acc.z *= dd; acc.w *= dd;
    if (bias) {
        int isbf = *flag; int c = g << 2;
        acc.x += ldw(bias, c, isbf); acc.y += ldw(bias, c + 1, isbf);
        acc.z += ldw(bias, c + 2, isbf); acc.w += ldw(bias, c + 3, isbf);
    }
    if (relu) {
        acc.x = fmaxf(acc.x, 0.f); acc.y = fmaxf(acc.y, 0.f);
        acc.z = fmaxf(acc.z, 0.f); acc.w = fmaxf(acc.w, 0.f);
    }
    ((float4*)out)[(long)d * G + g] = acc;
}

// sigma = Ahat @ 1
__global__ void k_sigacc(const int* __restrict__ src, const int* __restrict__ dst,
                         const float* __restrict__ dinv, float* __restrict__ sig, int E) {
    int e = blockIdx.x * 256 + threadIdx.x;
    if (e < E) atomicAdd(&sig[dst[e]], dinv[src[e]]);
}
__global__ void k_sigfin(float* __restrict__ sig, const float* __restrict__ dinv, int n) {
    int i = blockIdx.x * 256 + threadIdx.x;
    if (i < n) sig[i] = dinv[i] * (sig[i] + dinv[i]);
}
__global__ void k_rowvec_acc(const float* __restrict__ gmax, const void* __restrict__ W,
                             float* __restrict__ out, const int* __restrict__ flag) {
    int n = blockIdx.x * 256 + threadIdx.x;
    if (n >= 1024) return;
    const int isbf = *flag;
    int c0 = blockIdx.y * 128;
    float s = 0.f;
    for (int c = c0; c < c0 + 128; c++) s += gmax[c] * ldw(W, (long)c * 1024 + n, isbf);
    atomicAdd(&out[n], s);
}

// ---------------------------------------------------------------- batchnorm + relu (n<=1024)
__global__ __launch_bounds__(256) void k_bn(float* __restrict__ h, const void* __restrict__ gamma,
                                            const void* __restrict__ beta, int n, int C,
                                            const int* __restrict__ flag) {
    int c = blockIdx.x;
    int tid = threadIdx.x;
    __shared__ float sm[256];
    float v[4];
    float s = 0.f;
    #pragma unroll
    for (int u = 0; u < 4; u++) {
        int r = tid + u * 256;
        v[u] = (r < n) ? h[(long)r * C + c] : 0.f;
        s += v[u];
    }
    sm[tid] = s; __syncthreads();
    for (int o = 128; o > 0; o >>= 1) { if (tid < o) sm[tid] += sm[tid + o]; __syncthreads(); }
    float mu = sm[0] / n;
    __syncthreads();
    float s2 = 0.f;
    #pragma unroll
    for (int u = 0; u < 4; u++) {
        int r = tid + u * 256;
        if (r < n) { float d = v[u] - mu; s2 += d * d; }
    }
    sm[tid] = s2; __syncthreads();
    for (int o = 128; o > 0; o >>= 1) { if (tid < o) sm[tid] += sm[tid + o]; __syncthreads(); }
    float var = sm[0] / n;
    float rsq = rsqrtf(var + 1e-5f);
    float g = ldw(gamma, c, *flag), be = ldw(beta, c, *flag);
    #pragma unroll
    for (int u = 0; u < 4; u++) {
        int r = tid + u * 256;
        if (r < n) h[(long)r * C + c] = fmaxf((v[u] - mu) * rsq * g + be, 0.f);
    }
}

// column max of h(1024 x 2048): 32 blocks x 64 cols
__global__ __launch_bounds__(256) void k_cmax(const float* __restrict__ h, float* __restrict__ out) {
    __shared__ float sm[256];
    int coff = threadIdx.x & 63, rq = threadIdx.x >> 6;
    int c = blockIdx.x * 64 + coff;
    float m = -3.0e38f;
    for (int r = rq; r < 1024; r += 4) m = fmaxf(m, h[(long)r * 2048 + c]);
    sm[threadIdx.x] = m;
    __syncthreads();
    if (rq == 0) {
        m = fmaxf(fmaxf(sm[coff], sm[64 + coff]), fmaxf(sm[128 + coff], sm[192 + coff]));
        out[c] = m;
    }
}

// ---------------------------------------------------------------- gather / strided copy
__global__ void k_gather(const float* __restrict__ src, const int* __restrict__ idx,
                         float* __restrict__ dst, int n, int ncol, int ss, int ds, int doff) {
    long i = blockIdx.x * 256L + threadIdx.x;
    if (i < (long)n * ncol) {
        int r = (int)(i / ncol), c = (int)(i % ncol);
        dst[(long)r * ds + doff + c] = src[(long)idx[r] * ss + c];
    }
}
// copy with optional per-row scale (rmul may be nullptr)
__global__ void k_copy(const float* __restrict__ src, float* __restrict__ dst,
                       const float* __restrict__ rmul,
                       int n, int ncol, int ss, int ds, int doff) {
    long i = blockIdx.x * 256L + threadIdx.x;
    if (i < (long)n * ncol) {
        int r = (int)(i / ncol), c = (int)(i % ncol);
        float v = src[(long)r * ss + c];
        if (rmul) v *= rmul[r];
        dst[(long)r * ds + doff + c] = v;
    }
}

// ---------------------------------------------------------------- kNN (k=3), one wave per dst
// psrc packed as float4 (x,y,z,|p|^2); compare on r = ns - 2*dot (== d2 - nd).
// NOTE: top-3 insert is straight-line macro code — a by-reference lambda here
// spilled all state to scratch (VGPR 16->12, WRITE_SIZE 0.5->6.5MB, 2.4x slower).
__device__ __forceinline__ bool knn_better(float d, int i, float D, int I) {
    return d < D || (d == D && i < I);
}
#define KNN_INS(rv, sv)                                                              \
    if ((rv) < bd2) {                                                                \
        if ((rv) < bd0)      { bd2 = bd1; bi2 = bi1; bd1 = bd0; bi1 = bi0;           \
                               bd0 = (rv); bi0 = (sv); }                             \
        else if ((rv) < bd1) { bd2 = bd1; bi2 = bi1; bd1 = (rv); bi1 = (sv); }       \
        else                 { bd2 = (rv); bi2 = (sv); }                             \
    }
__global__ __launch_bounds__(256) void k_knn_w(const float* __restrict__ pdst,
                                               const float4* __restrict__ psrc4,
                                               int M, int Ns,
                                               int* __restrict__ kidx, float* __restrict__ kw) {
    int wid = (blockIdx.x * 256 + threadIdx.x) >> 6;
    int lane = threadIdx.x & 63;
    if (wid >= M) return;
    float x = pdst[wid * 3], y = pdst[wid * 3 + 1], z = pdst[wid * 3 + 2];
    float nd = fmaf(x, x, fmaf(y, y, z * z));
    float bd0 = 3.4e38f, bd1 = 3.4e38f, bd2 = 3.4e38f;
    int bi0 = 0x7fffffff, bi1 = 0x7fffffff, bi2 = 0x7fffffff;
    int s = lane;
    for (; s + 64 < Ns; s += 128) {
        float4 q0 = psrc4[s];
        float4 q1 = psrc4[s + 64];
        float r0 = fmaf(-2.f, fmaf(x, q0.x, fmaf(y, q0.y, z * q0.z)), q0.w);
        float r1 = fmaf(-2.f, fmaf(x, q1.x, fmaf(y, q1.y, z * q1.z)), q1.w);
        KNN_INS(r0, s);
        KNN_INS(r1, s + 64);
    }
    for (; s < Ns; s += 64) {
        float4 q = psrc4[s];
        float r = fmaf(-2.f, fmaf(x, q.x, fmaf(y, q.y, z * q.z)), q.w);
        KNN_INS(r, s);
    }
    #pragma unroll
    for (int off = 32; off >= 1; off >>= 1) {
        float od0 = __shfl_xor(bd0, off, 64); int oi0 = __shfl_xor(bi0, off, 64);
        float od1 = __shfl_xor(bd1, off, 64); int oi1 = __shfl_xor(bi1, off, 64);
        float od2 = __shfl_xor(bd2, off, 64); int oi2 = __shfl_xor(bi2, off, 64);
        float dq[3] = {od0, od1, od2}; int iq[3] = {oi0, oi1, oi2};
        #pragma unroll
        for (int q = 0; q < 3; q++) {
            float dd = dq[q]; int ii = iq[q];
            if (knn_better(dd, ii, bd0, bi0))      { bd2 = bd1; bi2 = bi1; bd1 = bd0; bi1 = bi0; bd0 = dd; bi0 = ii; }
            else if (knn_better(dd, ii, bd1, bi1)) { bd2 = bd1; bi2 = bi1; bd1 = dd; bi1 = ii; }
            else if (knn_better(dd, ii, bd2, bi2)) { bd2 = dd; bi2 = ii; }
        }
    }
    if (lane == 0) {
        kidx[wid * 3] = bi0; kidx[wid * 3 + 1] = bi1; kidx[wid * 3 + 2] = bi2;
        kw[wid * 3]     = 1.0f / fmaxf(nd + bd0, 1e-16f);
        kw[wid * 3 + 1] = 1.0f / fmaxf(nd + bd1, 1e-16f);
        kw[wid * 3 + 2] = 1.0f / fmaxf(nd + bd2, 1e-16f);
    }
}

__global__ void k_knn_apply4(const float* __restrict__ h, const int* __restrict__ kidx,
                             const float* __restrict__ kw, const float* __restrict__ rmul,
                             float* __restrict__ out,
                             int M, int C, int ds) {  // C%4==0, ds%4==0
    const int G = C >> 2;
    long i = blockIdx.x * 256L + threadIdx.x;
    if (i >= (long)M * G) return;
    int r = (int)(i / G), g = (int)(i % G);
    int i0 = kidx[r * 3], i1 = kidx[r * 3 + 1], i2 = kidx[r * 3 + 2];
    float w0 = kw[r * 3], w1 = kw[r * 3 + 1], w2 = kw[r * 3 + 2];
    float inv = 1.0f / (w0 + w1 + w2);
    const float4* h4 = (const float4*)h;
    float4 a = h4[(long)i0 * G + g], b = h4[(long)i1 * G + g], c = h4[(long)i2 * G + g];
    float4 o;
    o.x = (w0 * a.x + w1 * b.x + w2 * c.x) * inv;
    o.y = (w0 * a.y + w1 * b.y + w2 * c.y) * inv;
    o.z = (w0 * a.z + w1 * b.z + w2 * c.z) * inv;
    o.w = (w0 * a.w + w1 * b.w + w2 * c.w) * inv;
    if (rmul) {
        float dd = rmul[r];
        o.x *= dd; o.y *= dd; o.z *= dd; o.w *= dd;
    }
    *(float4*)&out[(long)r * ds + (g << 2)] = o;
}
__global__ void k_knn_apply2(const float* __restrict__ h, const int* __restrict__ kidx,
                             const float* __restrict__ kw, float* __restrict__ out,
                             int M, int C, int ds) {  // C%2==0, ds%2==0
    const int G = C >> 1;
    long i = blockIdx.x * 256L + threadIdx.x;
    if (i >= (long)M * G) return;
    int r = (int)(i / G), g = (int)(i % G);
    int i0 = kidx[r * 3], i1 = kidx[r * 3 + 1], i2 = kidx[r * 3 + 2];
    float w0 = kw[r * 3], w1 = kw[r * 3 + 1], w2 = kw[r * 3 + 2];
    float inv = 1.0f / (w0 + w1 + w2);
    const float2* h2 = (const float2*)h;
    float2 a = h2[(long)i0 * G + g], b = h2[(long)i1 * G + g], c = h2[(long)i2 * G + g];
    float2 o;
    o.x = (w0 * a.x + w1 * b.x + w2 * c.x) * inv;
    o.y = (w0 * a.y + w1 * b.y + w2 * c.y) * inv;
    *(float2*)&out[(long)r * ds + (g << 1)] = o;
}

// ---------------------------------------------------------------- launch
extern "C" void kernel_launch(void* const* d_in, const int* in_sizes, int n_in,
                              void* d_out, int out_size, void* d_ws, size_t ws_size,
                              hipStream_t stream) {
    const int N0 = 16384, N1 = 4096, N2 = 1024;
    const int E0 = in_sizes[48] / 2, E1 = in_sizes[49] / 2, E2 = in_sizes[50] / 2;

    const int* idx0 = (const int*)d_in[46];
    const int* idx1 = (const int*)d_in[47];
    const int* ei0  = (const int*)d_in[48];
    const int* ei1  = (const int*)d_in[49];
    const int* ei2  = (const int*)d_in[50];

    float* W = (float*)d_ws;
    size_t off = 0;
    auto alloc = [&](size_t nf) { float* p = W + off; off += (nf + 63) & ~(size_t)63; return p; };
    auto allocU = [&](size_t nu) { return (unsigned short*)alloc((nu + 1) / 2); };
    float* P     = alloc(4194304);   // 16384x256 == 4096x1024 == 1024x2048(+)
    float* Q     = alloc(4194304);
    float* CAT   = alloc(8486912);   // 16384x518 >= 16384x256 >= 4096x320
    float* xf    = alloc(98304);     // 16384x6 (also final 16384x4 out)
    float* posf  = alloc(49152);
    float* pos1  = alloc(12288);
    float* pos2  = alloc(3072);
    float* pos1p = alloc(16384);     // 4096 float4 packed
    float* pos2p = alloc(4096);      // 1024 float4 packed
    float* dinv0 = alloc(16384);
    float* dinv1 = alloc(4096);
    float* dinv2 = alloc(1024);
    float* x1    = alloc(262144);    // 4096x64
    float* c2    = alloc(134144);    // 1024x131
    float* xb    = alloc(262144);    // 1024x256
    float* gmaxb = alloc(2048);
    float* rowv  = alloc(1024);
    float* sigb  = alloc(4096);
    float* kwb   = alloc(49152);
    int*   kib   = (int*)alloc(49152);
    int*   flg   = (int*)alloc(64);
    int*   cntb  = (int*)alloc(16384);
    int*   offs0 = (int*)alloc(16448);
    int*   offs1 = (int*)alloc(4160);
    int*   offs2 = (int*)alloc(1088);
    int*   bkt0  = (int*)alloc(E0);
    int*   bkt1  = (int*)alloc(E1);
    int*   bkt2  = (int*)alloc(E2);

    // bf16 W^T hi/lo planes (N x Kpad each) — appended last; guard below disables
    // the MFMA path entirely if they don't fit in ws.
    struct WtPair { unsigned short *h, *l; int Kp; };
    auto mkwt = [&](size_t n, int Kp) {
        WtPair p; p.h = allocU(n); p.l = allocU(n); p.Kp = Kp; return p;
    };
    WtPair wt6  = mkwt(64 * 64, 64);
    WtPair wt8  = mkwt(64 * 128, 128);
    WtPair wt10 = mkwt(64 * 64, 64);
    WtPair wt12 = mkwt(128 * 64, 64);
    WtPair wt14 = mkwt(128 * 192, 192);
    WtPair wt16 = mkwt(128 * 128, 128);
    WtPair wt18 = mkwt(256 * 128, 128);
    WtPair wt20 = mkwt(512 * 192, 192);
    WtPair wt22 = mkwt(1024 * 512, 512);
    WtPair wt24 = mkwt(2048 * 1024, 1024);
    WtPair wt30 = mkwt(1024 * 320, 320);
    WtPair wt32 = mkwt(1024 * 1024, 1024);
    WtPair wt34 = mkwt(512 * 1024, 1024);
    WtPair wt36 = mkwt(256 * 576, 576);
    WtPair wt38 = mkwt(256 * 256, 256);
    WtPair wt40 = mkwt(128 * 256, 256);
    WtPair wt42 = mkwt(64 * 128, 128);

    const bool usex = (off * sizeof(float)) <= ws_size;

    auto g1 = [](long n) { return dim3((unsigned)((n + 255) / 256)); };

    auto mm = [&](const float* Ain, int iw, int ib, const float* radd, const float* rsc,
                  const float* rs, float* out, int M_, int K_, int N_, long woff, int relu) {
        dim3 g((N_ + 63) / 64, M_ / 64);
        k_mm<<<g, 256, 0, stream>>>(Ain, d_in[iw], ib >= 0 ? d_in[ib] : nullptr,
                                    radd, rsc, rs, out, M_, K_, N_, woff, relu, flg);
    };
    auto mmx = [&](const float* Ain, int iw, int ib, const float* radd, const float* rsc,
                   const float* rs, float* out, int M_, int K_, int N_, long woff, int relu,
                   const WtPair& wp) {
        if (usex) {
            dim3 g(N_ / 64, M_ / 64);
            k_mmx<<<g, 512, 0, stream>>>(Ain, wp.h, wp.l,
                                         ib >= 0 ? d_in[ib] : nullptr,
                                         radd, rsc, rs, out, M_, K_, wp.Kp, N_, relu, flg);
        } else {
            mm(Ain, iw, ib, radd, rsc, rs, out, M_, K_, N_, woff, relu);
        }
    };
    auto gcnx = [&](const float* Ain, int n, int K, int iw, int ib, int C,
                    const int* offs, const int* bkt, const float* dinv, float* t, float* out,
                    const WtPair& wp) {
        mmx(Ain, iw, -1, nullptr, nullptr, dinv, t, n, K, C, 0, 0, wp);
        k_aggr<<<g1((long)n * (C >> 2)), 256, 0, stream>>>(t, offs, bkt, dinv, d_in[ib],
                                                           out, n, C, 1, flg);
    };
    auto gcn = [&](const float* Ain, int n, int K, int iw, int ib, int C,
                   const int* offs, const int* bkt, const float* dinv, float* t, float* out) {
        mm(Ain, iw, -1, nullptr, nullptr, dinv, t, n, K, C, 0, 0);
        k_aggr<<<g1((long)n * (C >> 2)), 256, 0, stream>>>(t, offs, bkt, dinv, d_in[ib],
                                                           out, n, C, 1, flg);
    };
    auto csr = [&](const int* ei, int E, int n, int* offs, int* bkt, float* dinv) {
        k_zero_i<<<g1(n), 256, 0, stream>>>(cntb, n);
        k_count<<<g1(E), 256, 0, stream>>>(ei + E, cntb, E);
        k_dinv_i<<<g1(n), 256, 0, stream>>>(cntb, dinv, n);
        k_scan<<<1, 1024, 0, stream>>>(cntb, offs, n);
        k_zero_i<<<g1(n), 256, 0, stream>>>(cntb, n);
        k_fill<<<g1(E), 256, 0, stream>>>(ei, ei + E, offs, cntb, bkt, E);
    };
    auto wtk = [&](int iw, long woff, int K_, int N_, const WtPair& wp) {
        if (!usex) return;
        dim3 g(N_ / 32, wp.Kp / 32);
        k_wt<<<g, 256, 0, stream>>>(d_in[iw], woff, wp.h, wp.l, K_, N_, wp.Kp, flg);
    };

    // dtype detection + input conversion + CSR + weight transposes
    k_detect<<<1, 256, 0, stream>>>((const unsigned short*)d_in[2], in_sizes[2], flg);
    k_cvt_in<<<g1(N0 * 6), 256, 0, stream>>>(d_in[0], xf, N0 * 6, flg);
    k_cvt_in<<<g1(N0 * 3), 256, 0, stream>>>(d_in[1], posf, N0 * 3, flg);
    csr(ei0, E0, N0, offs0, bkt0, dinv0);
    csr(ei1, E1, N1, offs1, bkt1, dinv1);
    csr(ei2, E2, N2, offs2, bkt2, dinv2);
    wtk(6, 0, 32, 64, wt6);
    wtk(8, 0, 67, 64, wt8);
    wtk(10, 0, 64, 64, wt10);
    wtk(12, 0, 64, 128, wt12);
    wtk(14, 0, 131, 128, wt14);
    wtk(16, 0, 128, 128, wt16);
    wtk(18, 0, 128, 256, wt18);
    wtk(20, 0, 131, 512, wt20);
    wtk(22, 0, 512, 1024, wt22);
    wtk(24, 0, 1024, 2048, wt24);
    wtk(30, 2048L * 1024L, 320, 1024, wt30);
    wtk(32, 0, 1024, 1024, wt32);
    wtk(34, 0, 1024, 512, wt34);
    wtk(36, 0, 518, 256, wt36);
    wtk(38, 0, 256, 256, wt38);
    wtk(40, 0, 256, 128, wt40);
    wtk(42, 0, 128, 64, wt42);

    // SA1: 6->32->32->64 on level-0 graph  (N=32 layers stay fp32)
    gcn(xf, N0, 6, 2, 3, 32, offs0, bkt0, dinv0, P, Q);
    gcn(Q, N0, 32, 4, 5, 32, offs0, bkt0, dinv0, P, Q);
    gcnx(Q, N0, 32, 6, 7, 64, offs0, bkt0, dinv0, P, Q, wt6);
    k_gather<<<g1((long)N1 * 64), 256, 0, stream>>>(Q, idx0, x1, N1, 64, 64, 64, 0);
    k_gather<<<g1((long)N1 * 3), 256, 0, stream>>>(posf, idx0, pos1, N1, 3, 3, 3, 0);

    // SA2: [x1|pos1](67) -> 64->64->128 on level-1 graph
    k_copy<<<g1((long)N1 * 64), 256, 0, stream>>>(x1, P, nullptr, N1, 64, 64, 67, 0);
    k_copy<<<g1((long)N1 * 3), 256, 0, stream>>>(pos1, P, nullptr, N1, 3, 3, 67, 64);
    gcnx(P, N1, 67, 8, 9, 64, offs1, bkt1, dinv1, Q, P, wt8);
    gcnx(P, N1, 64, 10, 11, 64, offs1, bkt1, dinv1, Q, P, wt10);
    gcnx(P, N1, 64, 12, 13, 128, offs1, bkt1, dinv1, Q, P, wt12);
    k_gather<<<g1((long)N2 * 128), 256, 0, stream>>>(P, idx1, c2, N2, 128, 128, 131, 0);
    k_gather<<<g1((long)N2 * 3), 256, 0, stream>>>(pos1, idx1, pos2, N2, 3, 3, 3, 0);
    k_copy<<<g1((long)N2 * 3), 256, 0, stream>>>(pos2, c2, nullptr, N2, 3, 3, 131, 128);

    // bottleneck: 131 -> 128->128->256 on level-2 graph
    gcnx(c2, N2, 131, 14, 15, 128, offs2, bkt2, dinv2, P, Q, wt14);
    gcnx(Q, N2, 128, 16, 17, 128, offs2, bkt2, dinv2, P, Q, wt16);
    gcnx(Q, N2, 128, 18, 19, 256, offs2, bkt2, dinv2, P, xb, wt18);

    // GlobalSA
    mmx(c2, 20, 21, nullptr, nullptr, nullptr, P, N2, 131, 512, 0, 0, wt20);
    k_bn<<<dim3(512), 256, 0, stream>>>(P, d_in[26], d_in[27], N2, 512, flg);
    mmx(P, 22, 23, nullptr, nullptr, nullptr, Q, N2, 512, 1024, 0, 0, wt22);
    k_bn<<<dim3(1024), 256, 0, stream>>>(Q, d_in[28], d_in[29], N2, 1024, flg);
    mmx(Q, 24, 25, nullptr, nullptr, nullptr, P, N2, 1024, 2048, 0, 0, wt24);
    k_cmax<<<dim3(32), 256, 0, stream>>>(P, gmaxb);

    // FP2: out1 = relu( (Ahat [interp(xb)|x1]) @ W[2048:] + sigma*rowv + b )
    k_zero<<<g1(1024), 256, 0, stream>>>(rowv, 1024);
    k_rowvec_acc<<<dim3(4, 16), 256, 0, stream>>>(gmaxb, d_in[30], rowv, flg);
    k_pack4<<<g1(N1), 256, 0, stream>>>(pos1, (float4*)pos1p, N1);
    k_pack4<<<g1(N2), 256, 0, stream>>>(pos2, (float4*)pos2p, N2);
    k_knn_w<<<g1((long)N1 * 64), 256, 0, stream>>>(pos1, (const float4*)pos2p, N1, N2, kib, kwb);
    k_knn_apply4<<<g1((long)N1 * 64), 256, 0, stream>>>(xb, kib, kwb, dinv1, CAT, N1, 256, 320);
    k_copy<<<g1((long)N1 * 64), 256, 0, stream>>>(x1, CAT, dinv1, N1, 64, 64, 320, 256);
    k_aggr<<<g1((long)N1 * 80), 256, 0, stream>>>(CAT, offs1, bkt1, dinv1, nullptr,
                                                  P, N1, 320, 0, flg);
    k_zero<<<g1(N1), 256, 0, stream>>>(sigb, N1);
    k_sigacc<<<g1(E1), 256, 0, stream>>>(ei1, ei1 + E1, dinv1, sigb, E1);
    k_sigfin<<<g1(N1), 256, 0, stream>>>(sigb, dinv1, N1);
    mmx(P, 30, 31, rowv, sigb, nullptr, Q, N1, 320, 1024, 2048L * 1024L, 1, wt30);
    gcnx(Q, N1, 1024, 32, 33, 1024, offs1, bkt1, dinv1, P, Q, wt32);
    gcnx(Q, N1, 1024, 34, 35, 512, offs1, bkt1, dinv1, P, Q, wt34);  // Q: 4096x512

    // FP1
    k_knn_w<<<g1((long)N0 * 64), 256, 0, stream>>>(posf, (const float4*)pos1p, N0, N1, kib, kwb);
    k_knn_apply2<<<g1((long)N0 * 256), 256, 0, stream>>>(Q, kib, kwb, CAT, N0, 512, 518);
    k_copy<<<g1((long)N0 * 6), 256, 0, stream>>>(xf, CAT, nullptr, N0, 6, 6, 518, 512);
    gcnx(CAT, N0, 518, 36, 37, 256, offs0, bkt0, dinv0, P, Q, wt36);
    gcnx(Q, N0, 256, 38, 39, 256, offs0, bkt0, dinv0, P, CAT, wt38);
    gcnx(CAT, N0, 256, 40, 41, 128, offs0, bkt0, dinv0, P, Q, wt40);

    // final MLP: 128 -> 64 (relu) -> 4
    mmx(Q, 42, 43, nullptr, nullptr, nullptr, P, N0, 128, 64, 0, 1, wt42);
    mm(P, 44, 45, nullptr, nullptr, nullptr, xf, N0, 64, 4, 0, 0);
    k_out<<<g1(N0 * 4), 256, 0, stream>>>(xf, d_out, N0 * 4, flg);
}